// Round 13
// baseline (678.976 us; speedup 1.0000x reference)
//
#include <hip/hip_runtime.h>
#include <hip/hip_bf16.h>
#include <stdint.h>

#define B_  2
#define S_  2048
#define SC_ 512
#define H_  2048
#define NH_ 16
#define G_  8
#define D_  128

typedef __attribute__((ext_vector_type(8))) short bf16x8;
typedef __attribute__((ext_vector_type(8))) _Float16 f16x8;
typedef __attribute__((ext_vector_type(4))) float f32x4;
typedef __attribute__((ext_vector_type(8))) int i32x8;

// SCL * log2(e) = (1/sqrt(128)) * 1.4426950408889634
#define SCLLOG2E 0.12751741f
// |score_log2| <= SCLLOG2E * ||q|| * ||k|| = SCLLOG2E*128 = 16.3222 (LN => unit rows)
#define FIXED_M  16.34f

#define GLOAD_LDS16(g, l) __builtin_amdgcn_global_load_lds( \
    (const __attribute__((address_space(1))) uint32_t*)(g), \
    (__attribute__((address_space(3))) uint32_t*)(l), 16, 0, 0)

__device__ __forceinline__ uint16_t bf16_rne_bits(float x) {
  uint32_t u = __float_as_uint(x);
  u += 0x7fffu + ((u >> 16) & 1u);
  return (uint16_t)(u >> 16);
}
__device__ __forceinline__ float bf16_rne_f(float x) {
  uint32_t u = __float_as_uint(x);
  u += 0x7fffu + ((u >> 16) & 1u);
  return __uint_as_float(u & 0xffff0000u);
}
__device__ __forceinline__ uint16_t f16_bits(float x) {
  _Float16 h = (_Float16)x;
  return __builtin_bit_cast(uint16_t, h);
}
// fp8 e4m3fn round-trip (RNE, input already clipped to [-448,448])
__device__ __forceinline__ float fp8_rt(float x) {
  float a = fabsf(x);
  float step;
  if (a >= 0.015625f) {
    uint32_t u = __float_as_uint(a);
    int E = (int)((u >> 23) & 0xffu) - 127;
    step = __uint_as_float((uint32_t)(E - 3 + 127) << 23);
  } else {
    step = 0.001953125f;
  }
  float q = rintf(a / step) * step;
  return x < 0.f ? -q : q;
}
// exact e4m3fn encode of a value that is already an exact fp8 value
__device__ __forceinline__ uint8_t fp8_enc(float v) {
  uint32_t u = __float_as_uint(v);
  uint8_t s = (uint8_t)((u >> 24) & 0x80u);
  float a = fabsf(v);
  if (a == 0.f) return s;
  int E = (int)((u >> 23) & 0xffu) - 127;
  if (E < -6) return s | (uint8_t)(a * 512.f);        // subnormal: k * 2^-9
  uint32_t mant = (u >> 20) & 7u;
  return s | ((uint8_t)(E + 7) << 3) | (uint8_t)mant;
}

// ---------------- prep: weight encodes / splits / scalar scales --------------
__global__ __launch_bounds__(256) void k_prep(
    const float* __restrict__ wq, const float* __restrict__ wqx,
    const float* __restrict__ wk, const float* __restrict__ wv,
    const float* __restrict__ wkvx, const float* __restrict__ wproj,
    const float* __restrict__ cond,
    const float* __restrict__ q_is, const float* __restrict__ wq_s,
    const float* __restrict__ qx_is, const float* __restrict__ wqx_s,
    const float* __restrict__ k_is, const float* __restrict__ wk_s,
    const float* __restrict__ v_is, const float* __restrict__ wv_s,
    const float* __restrict__ p_is, const float* __restrict__ p_ws,
    uint8_t* __restrict__ Wcat, uint8_t* __restrict__ Wpb,
    uint16_t* __restrict__ Wkvxh, uint16_t* __restrict__ Wkvxl,
    uint16_t* __restrict__ condh, uint16_t* __restrict__ condl,
    float* __restrict__ scales)
{
  size_t idx = (size_t)blockIdx.x * 256 + threadIdx.x;
  size_t stride = (size_t)gridDim.x * 256;
  const size_t NC = (size_t)6144 * 2048;
  for (size_t i = idx; i < NC; i += stride) {
    size_t row = i >> 11; int col = (int)(i & 2047);
    float v;
    if (row < 2048)      v = wq[i];
    else if (row < 4096) v = wqx[(row - 2048) * 2048 + col];
    else if (row < 5120) v = wk[(row - 4096) * 2048 + col];
    else                 v = wv[(row - 5120) * 2048 + col];
    Wcat[i] = fp8_enc(v);
  }
  const size_t NP = (size_t)2048 * 4096;
  for (size_t i = idx; i < NP; i += stride)
    Wpb[i] = fp8_enc(wproj[i]);
  const size_t NX = (size_t)2048 * 2048;
  for (size_t i = idx; i < NX; i += stride) {
    float x = wkvx[i];
    uint16_t h = bf16_rne_bits(x);
    Wkvxh[i] = h;
    Wkvxl[i] = bf16_rne_bits(x - __uint_as_float((uint32_t)h << 16));
  }
  const size_t ND = (size_t)1024 * 2048;
  for (size_t i = idx; i < ND; i += stride) {
    float x = cond[i];
    uint16_t h = bf16_rne_bits(x);
    condh[i] = h;
    condl[i] = bf16_rne_bits(x - __uint_as_float((uint32_t)h << 16));
  }
  if (idx == 0) {
    scales[0] = q_is[0] * wq_s[0];
    scales[1] = qx_is[0] * wqx_s[0];
    scales[2] = k_is[0] * wk_s[0];
    scales[3] = v_is[0] * wv_s[0];
    scales[4] = p_is[0] * p_ws[0];
  }
}

// ---------------- hidden LayerNorm + fp8 quantize -> Aq (fp8 bytes) ----------
__global__ __launch_bounds__(256) void k_ln_quant(
    const float* __restrict__ x, const float* __restrict__ w,
    const float* __restrict__ b, const float* __restrict__ qis,
    uint8_t* __restrict__ Aq)
{
  int row = blockIdx.x;
  int tid = threadIdx.x;
  const float* xr = x + (size_t)row * H_;
  float v[8];
  float s = 0.f, sq = 0.f;
#pragma unroll
  for (int i = 0; i < 8; i++) {
    float t = xr[tid + i * 256];
    v[i] = t; s += t; sq += t * t;
  }
#pragma unroll
  for (int m = 1; m < 64; m <<= 1) { s += __shfl_xor(s, m); sq += __shfl_xor(sq, m); }
  __shared__ float red[8];
  int wv = tid >> 6;
  if ((tid & 63) == 0) { red[wv] = s; red[4 + wv] = sq; }
  __syncthreads();
  s = red[0] + red[1] + red[2] + red[3];
  sq = red[4] + red[5] + red[6] + red[7];
  float mu = s * (1.f / H_);
  float var = sq * (1.f / H_) - mu * mu;
  float rs = 1.0f / sqrtf(var + 1e-5f);
#pragma unroll
  for (int i = 0; i < 8; i++) {
    int c = tid + i * 256;
    float y = (v[i] - mu) * rs * w[c] + b[c];
    float t = y / qis[c];
    t = fminf(fmaxf(t, -448.f), 448.f);
    t = fp8_rt(bf16_rne_f(t));
    Aq[(size_t)row * H_ + c] = fp8_enc(t);
  }
}

// ---------------- MX-fp8 GEMM (B^T layout), K-step = 128 fp8 bytes -----------
// MODE 0: QKV proj -> per-head LN -> Q/Qx pre-scaled f16, K f16, V^T bf16
// MODE 2: out proj -> *scale -> f32 out
template <int MODE>
__global__ __launch_bounds__(256) void k_gemm8(
    const uint8_t* __restrict__ A, const uint8_t* __restrict__ Bm,
    int M, int N, int K,
    const float* __restrict__ scales,
    const float* __restrict__ qln_w, const float* __restrict__ qln_b,
    const float* __restrict__ kln_w, const float* __restrict__ kln_b,
    const float* __restrict__ qxln_w, const float* __restrict__ qxln_b,
    uint16_t* __restrict__ Qh,
    uint16_t* __restrict__ Qxh,
    uint16_t* __restrict__ Kf, uint16_t* __restrict__ Vtf,
    float* __restrict__ Cout)
{
  __shared__ __align__(64) uint8_t smem[128 * 136 * 2];  // >= 32768+2048 staging+sred
  uint8_t* lA = smem;
  uint8_t* lB = smem + 128 * 128;
  float* sred = (float*)(smem + 128 * 128 * 2);
  uint16_t* sT = (uint16_t*)smem;          // V-path overlay: 128*136*2 = 34816 B

  const int tid = threadIdx.x;
  const int lane = tid & 63;
  const int wv = tid >> 6;
  const int wr = wv >> 1, wc = wv & 1;
  const int l15 = lane & 15, l4 = lane >> 4;
  const int m0 = blockIdx.y * 128, n0 = blockIdx.x * 128;

  int srow[4]; int soff[4];
#pragma unroll
  for (int c = 0; c < 4; c++) {
    int i = c * 256 + tid;
    int row = i >> 3, s = i & 7;
    srow[c] = row;
    soff[c] = (((s >> 1) ^ (row & 3)) << 5) + ((s & 1) << 4);
  }
  const int axo = ((l4 ^ (l15 & 3)) << 5);

  f32x4 acc[4][4] = {};

  for (int kt = 0; kt < K; kt += 128) {
    __syncthreads();
#pragma unroll
    for (int c = 0; c < 4; c++) {
      GLOAD_LDS16(&A[(size_t)(m0 + srow[c]) * K + kt + soff[c]],
                  &lA[(c * 256 + wv * 64) * 16]);
      GLOAD_LDS16(&Bm[(size_t)(n0 + srow[c]) * K + kt + soff[c]],
                  &lB[(c * 256 + wv * 64) * 16]);
    }
    __syncthreads();
    i32x8 af[4];
#pragma unroll
    for (int mt = 0; mt < 4; mt++)
      af[mt] = *(i32x8*)&lA[(wr * 64 + mt * 16 + l15) * 128 + axo];
#pragma unroll
    for (int nt = 0; nt < 4; nt++) {
      i32x8 bf = *(i32x8*)&lB[(wc * 64 + nt * 16 + l15) * 128 + axo];
#pragma unroll
      for (int mt = 0; mt < 4; mt++)
        acc[mt][nt] = __builtin_amdgcn_mfma_scale_f32_16x16x128_f8f6f4(
            af[mt], bf, acc[mt][nt], 0, 0, 0, 0x7F7F7F7F, 0, 0x7F7F7F7F);
    }
  }

  const int cb = n0 >> 7;
  float sscale;
  const float *lw = nullptr, *lb = nullptr;
  if (MODE == 0) {
    int sect = (cb < 16) ? 0 : (cb < 32) ? 1 : (cb < 40) ? 2 : 3;
    sscale = scales[sect];
    if (sect == 0) { lw = qln_w; lb = qln_b; }
    else if (sect == 1) { lw = qxln_w; lb = qxln_b; }
    else if (sect == 2) { lw = kln_w; lb = kln_b; }
  } else {
    sscale = scales[4];
  }
#pragma unroll
  for (int mt = 0; mt < 4; mt++)
#pragma unroll
    for (int nt = 0; nt < 4; nt++)
#pragma unroll
      for (int j = 0; j < 4; j++) acc[mt][nt][j] *= sscale;

  if (MODE == 2) {
#pragma unroll
    for (int mt = 0; mt < 4; mt++)
#pragma unroll
      for (int j = 0; j < 4; j++) {
        int r = m0 + wr * 64 + mt * 16 + l4 * 4 + j;
#pragma unroll
        for (int nt = 0; nt < 4; nt++) {
          int c = n0 + wc * 64 + nt * 16 + l15;
          Cout[(size_t)r * N + c] = acc[mt][nt][j];
        }
      }
    return;
  }

  if (MODE == 0 && cb >= 40) {
    // V section: transpose through LDS, coalesced bf16 stores.
    __syncthreads();   // staging LDS no longer needed; safe to overlay
#pragma unroll
    for (int mt = 0; mt < 4; mt++)
#pragma unroll
      for (int j = 0; j < 4; j++) {
        int rl = wr * 64 + mt * 16 + l4 * 4 + j;
#pragma unroll
        for (int nt = 0; nt < 4; nt++) {
          int d = wc * 64 + nt * 16 + l15;
          sT[d * 136 + rl] = bf16_rne_bits(acc[mt][nt][j]);
        }
      }
    __syncthreads();
    int gg = cb - 40;
    int d = tid >> 1, rh = (tid & 1) << 6;
    size_t gbase = (((size_t)(m0 >> 11) * G_ + gg) * D_ + d) * (size_t)S_ +
                   (m0 & 2047) + rh;
    const uint16_t* sp = &sT[d * 136 + rh];
#pragma unroll
    for (int k = 0; k < 8; k++)
      *(bf16x8*)&Vtf[gbase + k * 8] = *(const bf16x8*)&sp[k * 8];
    return;
  }

  // Q / Qx / K sections: per-head LN over the 128-col tile
  float mu_[4][4], rs_[4][4];
#pragma unroll
  for (int mt = 0; mt < 4; mt++)
#pragma unroll
    for (int j = 0; j < 4; j++) {
      float s = 0.f, sq = 0.f;
#pragma unroll
      for (int nt = 0; nt < 4; nt++) { float t = acc[mt][nt][j]; s += t; sq += t * t; }
#pragma unroll
      for (int mm = 1; mm < 16; mm <<= 1) { s += __shfl_xor(s, mm); sq += __shfl_xor(sq, mm); }
      if (l15 == 0) {
        int ar = wr * 64 + mt * 16 + l4 * 4 + j;
        sred[wc * 128 + ar] = s;
        sred[256 + wc * 128 + ar] = sq;
      }
    }
  __syncthreads();
#pragma unroll
  for (int mt = 0; mt < 4; mt++)
#pragma unroll
    for (int j = 0; j < 4; j++) {
      int ar = wr * 64 + mt * 16 + l4 * 4 + j;
      float Sm = sred[ar] + sred[128 + ar];
      float Sq = sred[256 + ar] + sred[384 + ar];
      float mu = Sm * (1.f / 128.f);
      float var = Sq * (1.f / 128.f) - mu * mu;
      mu_[mt][j] = mu;
      rs_[mt][j] = 1.f / sqrtf(var + 1e-5f);
    }

#pragma unroll
  for (int mt = 0; mt < 4; mt++)
#pragma unroll
    for (int j = 0; j < 4; j++) {
      int r = m0 + wr * 64 + mt * 16 + l4 * 4 + j;
#pragma unroll
      for (int nt = 0; nt < 4; nt++) {
        int d = wc * 64 + nt * 16 + l15;
        float y = (acc[mt][nt][j] - mu_[mt][j]) * rs_[mt][j] * lw[d] + lb[d];
        if (cb < 32) y *= SCLLOG2E;   // fold softmax scale + log2e into Q/Qx
        uint16_t hb = f16_bits(y);
        if (cb < 16) {
          Qh[((size_t)r * NH_ + cb) * D_ + d] = hb;
        } else if (cb < 32) {
          Qxh[((size_t)r * NH_ + (cb - 16)) * D_ + d] = hb;
        } else {
          Kf[((size_t)r * G_ + (cb - 32)) * D_ + d] = hb;
        }
      }
    }
}

// ---------------- kvx GEMM: m97 structure, split A/B 3-MFMA, BM=64 -----------
__global__ __launch_bounds__(256) void k_kvx(
    const uint16_t* __restrict__ Ah, const uint16_t* __restrict__ Al,
    const uint16_t* __restrict__ Bh, const uint16_t* __restrict__ Bl,
    const float* __restrict__ kxln_w, const float* __restrict__ kxln_b,
    uint16_t* __restrict__ Kxf, uint16_t* __restrict__ Vxtf)
{
  const int K = 2048;
  __shared__ __align__(64) uint8_t smem[26624];
  uint16_t* lA  = (uint16_t*)smem;                 // 64*32*2  = 4096
  uint16_t* lA2 = (uint16_t*)(smem + 4096);        // 4096
  uint16_t* lB  = (uint16_t*)(smem + 8192);        // 128*32*2 = 8192
  uint16_t* lB2 = (uint16_t*)(smem + 16384);       // 8192
  float* sred = (float*)(smem + 24576);
  uint16_t* sT = (uint16_t*)smem;                  // Vx overlay: 128*72*2 = 18432

  const int tid = threadIdx.x;
  const int lane = tid & 63;
  const int wv = tid >> 6;
  const int wc = wv;
  const int l15 = lane & 15, l4 = lane >> 4;
  const int m0 = blockIdx.y * 64, n0 = blockIdx.x * 128;

  const int ar0 = tid >> 2, ag0 = (tid & 3) ^ (ar0 & 3);
  int brow[2], bcg[2];
#pragma unroll
  for (int c = 0; c < 2; c++) {
    int i = c * 256 + tid;
    brow[c] = i >> 2;
    bcg[c] = (i & 3) ^ (brow[c] & 3);
  }
  const int axo = ((l4 ^ (l15 & 3)) * 8);

  f32x4 acc[4][2] = {};

  for (int kt = 0; kt < K; kt += 32) {
    __syncthreads();
    GLOAD_LDS16(&Ah[(size_t)(m0 + ar0) * K + kt + ag0 * 8], &lA[(wv * 64) * 8]);
    GLOAD_LDS16(&Al[(size_t)(m0 + ar0) * K + kt + ag0 * 8], &lA2[(wv * 64) * 8]);
#pragma unroll
    for (int c = 0; c < 2; c++) {
      GLOAD_LDS16(&Bh[(size_t)(n0 + brow[c]) * K + kt + bcg[c] * 8],
                  &lB[(c * 256 + wv * 64) * 8]);
      GLOAD_LDS16(&Bl[(size_t)(n0 + brow[c]) * K + kt + bcg[c] * 8],
                  &lB2[(c * 256 + wv * 64) * 8]);
    }
    __syncthreads();
    bf16x8 af[4], af2[4];
#pragma unroll
    for (int mt = 0; mt < 4; mt++) {
      af[mt]  = *(bf16x8*)&lA[(mt * 16 + l15) * 32 + axo];
      af2[mt] = *(bf16x8*)&lA2[(mt * 16 + l15) * 32 + axo];
    }
#pragma unroll
    for (int nt = 0; nt < 2; nt++) {
      bf16x8 bh = *(bf16x8*)&lB[(wc * 32 + nt * 16 + l15) * 32 + axo];
      bf16x8 bl = *(bf16x8*)&lB2[(wc * 32 + nt * 16 + l15) * 32 + axo];
#pragma unroll
      for (int mt = 0; mt < 4; mt++) {
        acc[mt][nt] = __builtin_amdgcn_mfma_f32_16x16x32_bf16(af[mt], bh, acc[mt][nt], 0, 0, 0);
        acc[mt][nt] = __builtin_amdgcn_mfma_f32_16x16x32_bf16(af[mt], bl, acc[mt][nt], 0, 0, 0);
        acc[mt][nt] = __builtin_amdgcn_mfma_f32_16x16x32_bf16(af2[mt], bh, acc[mt][nt], 0, 0, 0);
      }
    }
  }

  const int cb = n0 >> 7;

  if (cb >= 8) {
    // Vx: transpose through LDS (pad 72 keeps 16B alignment), coalesced stores
    __syncthreads();
#pragma unroll
    for (int mt = 0; mt < 4; mt++)
#pragma unroll
      for (int j = 0; j < 4; j++) {
        int rl = mt * 16 + l4 * 4 + j;
#pragma unroll
        for (int nt = 0; nt < 2; nt++) {
          int d = wc * 32 + nt * 16 + l15;
          sT[d * 72 + rl] = bf16_rne_bits(acc[mt][nt][j]);
        }
      }
    __syncthreads();
    int gg = cb - 8;
    int d = tid >> 1, rh = (tid & 1) << 5;
    size_t gbase = (((size_t)(m0 >> 9) * G_ + gg) * D_ + d) * (size_t)SC_ +
                   (m0 & 511) + rh;
    const uint16_t* sp = &sT[d * 72 + rh];
#pragma unroll
    for (int k = 0; k < 4; k++)
      *(bf16x8*)&Vxtf[gbase + k * 8] = *(const bf16x8*)&sp[k * 8];
    return;
  }

  float mu_[4][4], rs_[4][4];
#pragma unroll
  for (int mt = 0; mt < 4; mt++)
#pragma unroll
    for (int j = 0; j < 4; j++) {
      float s = 0.f, sq = 0.f;
#pragma unroll
      for (int nt = 0; nt < 2; nt++) { float t = acc[mt][nt][j]; s += t; sq += t * t; }
#pragma unroll
      for (int mm = 1; mm < 16; mm <<= 1) { s += __shfl_xor(s, mm); sq += __shfl_xor(sq, mm); }
      if (l15 == 0) {
        int ar = mt * 16 + l4 * 4 + j;
        sred[wc * 64 + ar] = s;
        sred[256 + wc * 64 + ar] = sq;
      }
    }
  __syncthreads();
#pragma unroll
  for (int mt = 0; mt < 4; mt++)
#pragma unroll
    for (int j = 0; j < 4; j++) {
      int ar = mt * 16 + l4 * 4 + j;
      float Sm = sred[ar] + sred[64 + ar] + sred[128 + ar] + sred[192 + ar];
      float Sq = sred[256 + ar] + sred[320 + ar] + sred[384 + ar] + sred[448 + ar];
      float mu = Sm * (1.f / 128.f);
      float var = Sq * (1.f / 128.f) - mu * mu;
      mu_[mt][j] = mu;
      rs_[mt][j] = 1.f / sqrtf(var + 1e-5f);
    }

#pragma unroll
  for (int mt = 0; mt < 4; mt++)
#pragma unroll
    for (int j = 0; j < 4; j++) {
      int r = m0 + mt * 16 + l4 * 4 + j;
#pragma unroll
      for (int nt = 0; nt < 2; nt++) {
        int d = wc * 32 + nt * 16 + l15;
        float y = (acc[mt][nt][j] - mu_[mt][j]) * rs_[mt][j] * kxln_w[d] + kxln_b[d];
        Kxf[((size_t)r * G_ + cb) * D_ + d] = f16_bits(y);
      }
    }
}

// ---------------- merged flash GQA attention (8-wave, QBLK=128, balanced) ----
// z: 0,1 = self (1 q-tile, T=2048); z: 2,3 = cross (x<4 only; 4 q-tiles each,
// T=512) -> 640 equal-duration blocks, no tail. Flash body = R9-exact.
__global__ __launch_bounds__(512) void k_attn(
    const uint16_t* __restrict__ Qs, const uint16_t* __restrict__ Qx,
    const uint16_t* __restrict__ Ks, const uint16_t* __restrict__ Vs,
    const uint16_t* __restrict__ Kx, const uint16_t* __restrict__ Vx,
    const float* __restrict__ smooth, uint8_t* __restrict__ catq)
{
  __shared__ __align__(16) uint16_t lK[2][32 * 128];   // 16 KB
  __shared__ __align__(16) uint16_t lV[2][128 * 32];   // 16 KB
  __shared__ __align__(16) uint16_t lP[128 * 32];      // 8 KB

  const int tid = threadIdx.x, lane = tid & 63, wv = tid >> 6;  // wv 0..7
  const int l15 = lane & 15, l4 = lane >> 4;
  const int h = blockIdx.y;
  const int zb = blockIdx.z;
  const int b = zb & 1;
  const bool xr = zb >= 2;
  if (xr && blockIdx.x >= 4) return;   // balanced grid: only 4 x-slots for cross
  const uint16_t* __restrict__ Q = xr ? Qx : Qs;
  const uint16_t* __restrict__ Kp = xr ? Kx : Ks;
  const uint16_t* __restrict__ Vp = xr ? Vx : Vs;
  const int T = xr ? SC_ : S_;
  const int colOff = xr ? 2048 : 0;
  const int g = h >> 1;

  // staging: 512 threads, 1 chunk (16 B) each for K and V
  const int krow = tid >> 4, kcg = (tid & 15) ^ (krow & 7);
  const int vrow = tid >> 2, vcg = (tid & 3) ^ (vrow & 3);

  // paired-column K mapping: output col l15 of MFMA nt <-> K row t = 2*l15+nt.
  int koff[2][4];
#pragma unroll
  for (int nt = 0; nt < 2; nt++)
#pragma unroll
    for (int ks = 0; ks < 4; ks++) {
      int t = 2 * l15 + nt;
      koff[nt][ks] = t * 128 + (((ks * 4 + l4) ^ (t & 7)) * 8);
    }
  const int vxo = (l4 ^ (l15 & 3)) * 8;

  const f32x4 CINIT = {-FIXED_M, -FIXED_M, -FIXED_M, -FIXED_M};
  const size_t kbase0 = ((size_t)b * T + krow) * (G_ * D_) + (size_t)g * D_ + kcg * 8;
  const size_t vbase0 = (((size_t)b * G_ + g) * (size_t)D_ + vrow) * (size_t)T + vcg * 8;
  const int nT = T >> 5;

  auto flash = [&](int q0) {
    f16x8 qf[4];
    {
      int srow = q0 + wv * 16 + l15;
      size_t base = (((size_t)b * S_ + srow) * NH_ + h) * (size_t)D_ + l4 * 8;
#pragma unroll
      for (int ks = 0; ks < 4; ks++)
        qf[ks] = *(const f16x8*)&Q[base + ks * 32];
    }

    float lsump[4] = {0.f, 0.f, 0.f, 0.f};
    f32x4 oacc[8] = {};

    const uint16_t* pK = Kp + kbase0;
    const uint16_t* pV = Vp + vbase0;

    // prologue: stage tile 0 into buf 0 (safe: stragglers of the previous
    // q-tile only read buf (nT-1)&1 == 1 and lP after their own PV)
    GLOAD_LDS16(pK, &lK[0][(wv * 64) * 8]);
    GLOAD_LDS16(pV, &lV[0][(wv * 64) * 8]);
    pK += 32 * G_ * D_;
    pV += 32;

    for (int tt = 0; tt < nT; tt++) {
      const int cur = tt & 1;
      __syncthreads();
      if (tt + 1 < nT) {
        GLOAD_LDS16(pK, &lK[cur ^ 1][(wv * 64) * 8]);
        GLOAD_LDS16(pV, &lV[cur ^ 1][(wv * 64) * 8]);
        pK += 32 * G_ * D_;
        pV += 32;
      }

      f32x4 sf[2];
      __builtin_amdgcn_s_setprio(1);
#pragma unroll
      for (int nt = 0; nt < 2; nt++) {
        f16x8 kf0 = *(f16x8*)&lK[cur][koff[nt][0]];
        f32x4 a = __builtin_amdgcn_mfma_f32_16x16x32_f16(qf[0], kf0, CINIT, 0, 0, 0);
#pragma unroll
        for (int ks = 1; ks < 4; ks++) {
          f16x8 kf = *(f16x8*)&lK[cur][koff[nt][ks]];
          a = __builtin_amdgcn_mfma_f32_16x16x32_f16(qf[ks], kf, a, 0, 0, 0);
        }
        sf[nt] = a;
      }
      __builtin_amdgcn_s_setprio(0);

      // branchless softmax: p = exp2(s - M), M folded into MFMA C-init
#pragma unroll
      for (int j = 0; j < 4; j++) {
        float p0 = __builtin_amdgcn_exp2f(sf[0][j]);
        float p1 = __builtin_amdgcn_exp2f(sf[1][j]);
        lsump[j] += p0 + p1;
        int prow = wv * 16 + l4 * 4 + j;
        uint32_t pk;
        asm("v_cvt_pk_bf16_f32 %0, %1, %2" : "=v"(pk) : "v"(p0), "v"(p1));
        *(uint32_t*)&lP[prow * 32 + l15 * 2] = pk;   // cols 2*l15, 2*l15+1
      }

      bf16x8 pa = *(bf16x8*)&lP[(wv * 16 + l15) * 32 + l4 * 8];
      __builtin_amdgcn_s_setprio(1);
#pragma unroll
      for (int dt = 0; dt < 8; dt++) {
        bf16x8 vh = *(bf16x8*)&lV[cur][(dt * 16 + l15) * 32 + vxo];
        oacc[dt] = __builtin_amdgcn_mfma_f32_16x16x32_bf16(pa, vh, oacc[dt], 0, 0, 0);
      }
      __builtin_amdgcn_s_setprio(0);
    }

#pragma unroll
    for (int j = 0; j < 4; j++) {
      float rsum = lsump[j];
#pragma unroll
      for (int mm = 1; mm < 16; mm <<= 1) rsum += __shfl_xor(rsum, mm);
      float inv = 1.f / rsum;
      int srow = q0 + wv * 16 + l4 * 4 + j;
      size_t rbase = ((size_t)b * S_ + srow) * 4096;
#pragma unroll
      for (int dt = 0; dt < 8; dt++) {
        int c = colOff + h * D_ + dt * 16 + l15;
        float t = (oacc[dt][j] * inv) / smooth[c];
        t = fminf(fmaxf(t, -448.f), 448.f);
        t = fp8_rt(bf16_rne_f(t));
        catq[rbase + c] = fp8_enc(t);
      }
    }
    // ensure all waves done with lP/lV[1] before next q-tile's prologue
    __syncthreads();
  };

  if (!xr) {
    flash(blockIdx.x * 128);
  } else {
#pragma unroll
    for (int qi = 0; qi < 4; qi++)
      flash((blockIdx.x * 4 + qi) * 128);
  }
}

// ---------------------------------------------------------------------------
extern "C" void kernel_launch(void* const* d_in, const int* in_sizes, int n_in,
                              void* d_out, int out_size, void* d_ws, size_t ws_size,
                              hipStream_t stream)
{
  (void)in_sizes; (void)n_in; (void)out_size;
  const float* hidden = (const float*)d_in[0];
  const float* cond   = (const float*)d_in[1];
  const float* ln_w   = (const float*)d_in[2];
  const float* ln_b   = (const float*)d_in[3];
  const float* wq     = (const float*)d_in[4];
  const float* wq_s   = (const float*)d_in[5];
  const float* q_is   = (const float*)d_in[6];
  const float* wqx    = (const float*)d_in[7];
  const float* wqx_s  = (const float*)d_in[8];
  const float* qx_is  = (const float*)d_in[9];
  const float* wk     = (const float*)d_in[10];
  const float* wk_s   = (const float*)d_in[11];
  const float* k_is   = (const float*)d_in[12];
  const float* wv     = (const float*)d_in[13];
  const float* wv_s   = (const float*)d_in[14];
  const float* v_is   = (const float*)d_in[15];
  const float* wkvx   = (const float*)d_in[16];
  const float* qln_w  = (const float*)d_in[17];
  const float* qln_b  = (const float*)d_in[18];
  const float* kln_w  = (const float*)d_in[19];
  const float* kln_b  = (const float*)d_in[20];
  const float* qxln_w = (const float*)d_in[21];
  const float* qxln_b = (const float*)d_in[22];
  const float* kxln_w = (const float*)d_in[23];
  const float* kxln_b = (const float*)d_in[24];
  const float* wproj  = (const float*)d_in[25];
  const float* p_ws   = (const float*)d_in[26];
  const float* p_is   = (const float*)d_in[27];
  const float* smooth = (const float*)d_in[28];

  char* ws = (char*)d_ws;
  size_t off = 0;
  auto alloc = [&](size_t bytes) {
    char* p = ws + off;
    off += (bytes + 255) & ~(size_t)255;
    return p;
  };
  uint8_t*  Aq    = (uint8_t*)alloc((size_t)4096 * 2048);
  uint8_t*  Wcat  = (uint8_t*)alloc((size_t)6144 * 2048);
  uint8_t*  Wpb   = (uint8_t*)alloc((size_t)2048 * 4096);
  uint16_t* Wkvxh = (uint16_t*)alloc((size_t)2048 * 2048 * 2);
  uint16_t* Wkvxl = (uint16_t*)alloc((size_t)2048 * 2048 * 2);
  uint16_t* condh = (uint16_t*)alloc((size_t)1024 * 2048 * 2);
  uint16_t* condl = (uint16_t*)alloc((size_t)1024 * 2048 * 2);
  uint16_t* Qh    = (uint16_t*)alloc((size_t)4096 * 16 * 128 * 2);
  uint16_t* Qxh   = (uint16_t*)alloc((size_t)4096 * 16 * 128 * 2);
  uint16_t* Kf    = (uint16_t*)alloc((size_t)4096 * 8 * 128 * 2);
  uint16_t* Vtf   = (uint16_t*)alloc((size_t)4096 * 8 * 128 * 2);
  uint16_t* Kxf   = (uint16_t*)alloc((size_t)1024 * 8 * 128 * 2);
  uint16_t* Vxtf  = (uint16_t*)alloc((size_t)1024 * 8 * 128 * 2);
  uint8_t*  catq  = (uint8_t*)alloc((size_t)4096 * 4096);
  float* scales   = (float*)alloc(256);
  if (ws_size < off) return;

  k_prep<<<2048, 256, 0, stream>>>(wq, wqx, wk, wv, wkvx, wproj, cond,
      q_is, wq_s, qx_is, wqx_s, k_is, wk_s, v_is, wv_s, p_is, p_ws,
      Wcat, Wpb, Wkvxh, Wkvxl, condh, condl, scales);

  k_ln_quant<<<4096, 256, 0, stream>>>(hidden, ln_w, ln_b, q_is, Aq);

  k_gemm8<0><<<dim3(48, 32), 256, 0, stream>>>(Aq, Wcat,
      4096, 6144, 2048, scales, qln_w, qln_b, kln_w, kln_b, qxln_w, qxln_b,
      Qh, Qxh, Kf, Vtf, nullptr);

  k_kvx<<<dim3(16, 16), 256, 0, stream>>>(condh, condl, Wkvxh, Wkvxl,
      kxln_w, kxln_b, Kxf, Vxtf);

  k_attn<<<dim3(16, 16, 4), 512, 0, stream>>>(Qh, Qxh, Kf, Vtf, Kxf, Vxtf,
      smooth, catq);

  k_gemm8<2><<<dim3(16, 32), 256, 0, stream>>>(catq, Wpb,
      4096, 2048, 4096, scales, nullptr, nullptr, nullptr, nullptr, nullptr, nullptr,
      nullptr, nullptr, nullptr, nullptr,
      (float*)d_out);
}

// Round 14
// 475.989 us; speedup vs baseline: 1.4265x; 1.4265x over previous
//
#include <hip/hip_runtime.h>
#include <hip/hip_bf16.h>
#include <stdint.h>

#define B_  2
#define S_  2048
#define SC_ 512
#define H_  2048
#define NH_ 16
#define G_  8
#define D_  128

typedef __attribute__((ext_vector_type(8))) short bf16x8;
typedef __attribute__((ext_vector_type(8))) _Float16 f16x8;
typedef __attribute__((ext_vector_type(4))) float f32x4;
typedef __attribute__((ext_vector_type(8))) int i32x8;

// SCL * log2(e) = (1/sqrt(128)) * 1.4426950408889634
#define SCLLOG2E 0.12751741f
// |score_log2| <= SCLLOG2E * ||q|| * ||k|| = SCLLOG2E*128 = 16.3222 (LN => unit rows)
#define FIXED_M  16.34f

#define GLOAD_LDS16(g, l) __builtin_amdgcn_global_load_lds( \
    (const __attribute__((address_space(1))) uint32_t*)(g), \
    (__attribute__((address_space(3))) uint32_t*)(l), 16, 0, 0)

__device__ __forceinline__ uint16_t bf16_rne_bits(float x) {
  uint32_t u = __float_as_uint(x);
  u += 0x7fffu + ((u >> 16) & 1u);
  return (uint16_t)(u >> 16);
}
__device__ __forceinline__ float bf16_rne_f(float x) {
  uint32_t u = __float_as_uint(x);
  u += 0x7fffu + ((u >> 16) & 1u);
  return __uint_as_float(u & 0xffff0000u);
}
__device__ __forceinline__ uint16_t f16_bits(float x) {
  _Float16 h = (_Float16)x;
  return __builtin_bit_cast(uint16_t, h);
}
// fp8 e4m3fn round-trip (RNE, input already clipped to [-448,448])
__device__ __forceinline__ float fp8_rt(float x) {
  float a = fabsf(x);
  float step;
  if (a >= 0.015625f) {
    uint32_t u = __float_as_uint(a);
    int E = (int)((u >> 23) & 0xffu) - 127;
    step = __uint_as_float((uint32_t)(E - 3 + 127) << 23);
  } else {
    step = 0.001953125f;
  }
  float q = rintf(a / step) * step;
  return x < 0.f ? -q : q;
}
// exact e4m3fn encode of a value that is already an exact fp8 value
__device__ __forceinline__ uint8_t fp8_enc(float v) {
  uint32_t u = __float_as_uint(v);
  uint8_t s = (uint8_t)((u >> 24) & 0x80u);
  float a = fabsf(v);
  if (a == 0.f) return s;
  int E = (int)((u >> 23) & 0xffu) - 127;
  if (E < -6) return s | (uint8_t)(a * 512.f);        // subnormal: k * 2^-9
  uint32_t mant = (u >> 20) & 7u;
  return s | ((uint8_t)(E + 7) << 3) | (uint8_t)mant;
}

// ---------------- prep: weight encodes / splits / scalar scales --------------
__global__ __launch_bounds__(256) void k_prep(
    const float* __restrict__ wq, const float* __restrict__ wqx,
    const float* __restrict__ wk, const float* __restrict__ wv,
    const float* __restrict__ wkvx, const float* __restrict__ wproj,
    const float* __restrict__ cond,
    const float* __restrict__ q_is, const float* __restrict__ wq_s,
    const float* __restrict__ qx_is, const float* __restrict__ wqx_s,
    const float* __restrict__ k_is, const float* __restrict__ wk_s,
    const float* __restrict__ v_is, const float* __restrict__ wv_s,
    const float* __restrict__ p_is, const float* __restrict__ p_ws,
    uint8_t* __restrict__ Wcat, uint8_t* __restrict__ Wpb,
    uint16_t* __restrict__ Wkvxh, uint16_t* __restrict__ Wkvxl,
    uint16_t* __restrict__ condh, uint16_t* __restrict__ condl,
    float* __restrict__ scales)
{
  size_t idx = (size_t)blockIdx.x * 256 + threadIdx.x;
  size_t stride = (size_t)gridDim.x * 256;
  const size_t NC = (size_t)6144 * 2048;
  for (size_t i = idx; i < NC; i += stride) {
    size_t row = i >> 11; int col = (int)(i & 2047);
    float v;
    if (row < 2048)      v = wq[i];
    else if (row < 4096) v = wqx[(row - 2048) * 2048 + col];
    else if (row < 5120) v = wk[(row - 4096) * 2048 + col];
    else                 v = wv[(row - 5120) * 2048 + col];
    Wcat[i] = fp8_enc(v);
  }
  const size_t NP = (size_t)2048 * 4096;
  for (size_t i = idx; i < NP; i += stride)
    Wpb[i] = fp8_enc(wproj[i]);
  const size_t NX = (size_t)2048 * 2048;
  for (size_t i = idx; i < NX; i += stride) {
    float x = wkvx[i];
    uint16_t h = bf16_rne_bits(x);
    Wkvxh[i] = h;
    Wkvxl[i] = bf16_rne_bits(x - __uint_as_float((uint32_t)h << 16));
  }
  const size_t ND = (size_t)1024 * 2048;
  for (size_t i = idx; i < ND; i += stride) {
    float x = cond[i];
    uint16_t h = bf16_rne_bits(x);
    condh[i] = h;
    condl[i] = bf16_rne_bits(x - __uint_as_float((uint32_t)h << 16));
  }
  if (idx == 0) {
    scales[0] = q_is[0] * wq_s[0];
    scales[1] = qx_is[0] * wqx_s[0];
    scales[2] = k_is[0] * wk_s[0];
    scales[3] = v_is[0] * wv_s[0];
    scales[4] = p_is[0] * p_ws[0];
  }
}

// ---------------- hidden LayerNorm + fp8 quantize -> Aq (fp8 bytes) ----------
__global__ __launch_bounds__(256) void k_ln_quant(
    const float* __restrict__ x, const float* __restrict__ w,
    const float* __restrict__ b, const float* __restrict__ qis,
    uint8_t* __restrict__ Aq)
{
  int row = blockIdx.x;
  int tid = threadIdx.x;
  const float* xr = x + (size_t)row * H_;
  float v[8];
  float s = 0.f, sq = 0.f;
#pragma unroll
  for (int i = 0; i < 8; i++) {
    float t = xr[tid + i * 256];
    v[i] = t; s += t; sq += t * t;
  }
#pragma unroll
  for (int m = 1; m < 64; m <<= 1) { s += __shfl_xor(s, m); sq += __shfl_xor(sq, m); }
  __shared__ float red[8];
  int wv = tid >> 6;
  if ((tid & 63) == 0) { red[wv] = s; red[4 + wv] = sq; }
  __syncthreads();
  s = red[0] + red[1] + red[2] + red[3];
  sq = red[4] + red[5] + red[6] + red[7];
  float mu = s * (1.f / H_);
  float var = sq * (1.f / H_) - mu * mu;
  float rs = 1.0f / sqrtf(var + 1e-5f);
#pragma unroll
  for (int i = 0; i < 8; i++) {
    int c = tid + i * 256;
    float y = (v[i] - mu) * rs * w[c] + b[c];
    float t = y / qis[c];
    t = fminf(fmaxf(t, -448.f), 448.f);
    t = fp8_rt(bf16_rne_f(t));
    Aq[(size_t)row * H_ + c] = fp8_enc(t);
  }
}

// ---------------- MX-fp8 GEMM (B^T layout), K-step = 128 fp8 bytes -----------
// MODE 0: QKV proj -> per-head LN -> Q/Qx pre-scaled f16, K f16, V^T bf16
// MODE 2: out proj -> *scale -> f32 out
template <int MODE>
__global__ __launch_bounds__(256) void k_gemm8(
    const uint8_t* __restrict__ A, const uint8_t* __restrict__ Bm,
    int M, int N, int K,
    const float* __restrict__ scales,
    const float* __restrict__ qln_w, const float* __restrict__ qln_b,
    const float* __restrict__ kln_w, const float* __restrict__ kln_b,
    const float* __restrict__ qxln_w, const float* __restrict__ qxln_b,
    uint16_t* __restrict__ Qh,
    uint16_t* __restrict__ Qxh,
    uint16_t* __restrict__ Kf, uint16_t* __restrict__ Vtf,
    float* __restrict__ Cout)
{
  __shared__ __align__(64) uint8_t smem[128 * 136 * 2];  // >= 32768+2048 staging+sred
  uint8_t* lA = smem;
  uint8_t* lB = smem + 128 * 128;
  float* sred = (float*)(smem + 128 * 128 * 2);
  uint16_t* sT = (uint16_t*)smem;          // V-path overlay: 128*136*2 = 34816 B

  const int tid = threadIdx.x;
  const int lane = tid & 63;
  const int wv = tid >> 6;
  const int wr = wv >> 1, wc = wv & 1;
  const int l15 = lane & 15, l4 = lane >> 4;
  const int m0 = blockIdx.y * 128, n0 = blockIdx.x * 128;

  int srow[4]; int soff[4];
#pragma unroll
  for (int c = 0; c < 4; c++) {
    int i = c * 256 + tid;
    int row = i >> 3, s = i & 7;
    srow[c] = row;
    soff[c] = (((s >> 1) ^ (row & 3)) << 5) + ((s & 1) << 4);
  }
  const int axo = ((l4 ^ (l15 & 3)) << 5);

  f32x4 acc[4][4] = {};

  for (int kt = 0; kt < K; kt += 128) {
    __syncthreads();
#pragma unroll
    for (int c = 0; c < 4; c++) {
      GLOAD_LDS16(&A[(size_t)(m0 + srow[c]) * K + kt + soff[c]],
                  &lA[(c * 256 + wv * 64) * 16]);
      GLOAD_LDS16(&Bm[(size_t)(n0 + srow[c]) * K + kt + soff[c]],
                  &lB[(c * 256 + wv * 64) * 16]);
    }
    __syncthreads();
    i32x8 af[4];
#pragma unroll
    for (int mt = 0; mt < 4; mt++)
      af[mt] = *(i32x8*)&lA[(wr * 64 + mt * 16 + l15) * 128 + axo];
#pragma unroll
    for (int nt = 0; nt < 4; nt++) {
      i32x8 bf = *(i32x8*)&lB[(wc * 64 + nt * 16 + l15) * 128 + axo];
#pragma unroll
      for (int mt = 0; mt < 4; mt++)
        acc[mt][nt] = __builtin_amdgcn_mfma_scale_f32_16x16x128_f8f6f4(
            af[mt], bf, acc[mt][nt], 0, 0, 0, 0x7F7F7F7F, 0, 0x7F7F7F7F);
    }
  }

  const int cb = n0 >> 7;
  float sscale;
  const float *lw = nullptr, *lb = nullptr;
  if (MODE == 0) {
    int sect = (cb < 16) ? 0 : (cb < 32) ? 1 : (cb < 40) ? 2 : 3;
    sscale = scales[sect];
    if (sect == 0) { lw = qln_w; lb = qln_b; }
    else if (sect == 1) { lw = qxln_w; lb = qxln_b; }
    else if (sect == 2) { lw = kln_w; lb = kln_b; }
  } else {
    sscale = scales[4];
  }
#pragma unroll
  for (int mt = 0; mt < 4; mt++)
#pragma unroll
    for (int nt = 0; nt < 4; nt++)
#pragma unroll
      for (int j = 0; j < 4; j++) acc[mt][nt][j] *= sscale;

  if (MODE == 2) {
#pragma unroll
    for (int mt = 0; mt < 4; mt++)
#pragma unroll
      for (int j = 0; j < 4; j++) {
        int r = m0 + wr * 64 + mt * 16 + l4 * 4 + j;
#pragma unroll
        for (int nt = 0; nt < 4; nt++) {
          int c = n0 + wc * 64 + nt * 16 + l15;
          Cout[(size_t)r * N + c] = acc[mt][nt][j];
        }
      }
    return;
  }

  if (MODE == 0 && cb >= 40) {
    // V section: transpose through LDS, coalesced bf16 stores.
    __syncthreads();   // staging LDS no longer needed; safe to overlay
#pragma unroll
    for (int mt = 0; mt < 4; mt++)
#pragma unroll
      for (int j = 0; j < 4; j++) {
        int rl = wr * 64 + mt * 16 + l4 * 4 + j;
#pragma unroll
        for (int nt = 0; nt < 4; nt++) {
          int d = wc * 64 + nt * 16 + l15;
          sT[d * 136 + rl] = bf16_rne_bits(acc[mt][nt][j]);
        }
      }
    __syncthreads();
    int gg = cb - 40;
    int d = tid >> 1, rh = (tid & 1) << 6;
    size_t gbase = (((size_t)(m0 >> 11) * G_ + gg) * D_ + d) * (size_t)S_ +
                   (m0 & 2047) + rh;
    const uint16_t* sp = &sT[d * 136 + rh];
#pragma unroll
    for (int k = 0; k < 8; k++)
      *(bf16x8*)&Vtf[gbase + k * 8] = *(const bf16x8*)&sp[k * 8];
    return;
  }

  // Q / Qx / K sections: per-head LN over the 128-col tile
  float mu_[4][4], rs_[4][4];
#pragma unroll
  for (int mt = 0; mt < 4; mt++)
#pragma unroll
    for (int j = 0; j < 4; j++) {
      float s = 0.f, sq = 0.f;
#pragma unroll
      for (int nt = 0; nt < 4; nt++) { float t = acc[mt][nt][j]; s += t; sq += t * t; }
#pragma unroll
      for (int mm = 1; mm < 16; mm <<= 1) { s += __shfl_xor(s, mm); sq += __shfl_xor(sq, mm); }
      if (l15 == 0) {
        int ar = wr * 64 + mt * 16 + l4 * 4 + j;
        sred[wc * 128 + ar] = s;
        sred[256 + wc * 128 + ar] = sq;
      }
    }
  __syncthreads();
#pragma unroll
  for (int mt = 0; mt < 4; mt++)
#pragma unroll
    for (int j = 0; j < 4; j++) {
      int ar = wr * 64 + mt * 16 + l4 * 4 + j;
      float Sm = sred[ar] + sred[128 + ar];
      float Sq = sred[256 + ar] + sred[384 + ar];
      float mu = Sm * (1.f / 128.f);
      float var = Sq * (1.f / 128.f) - mu * mu;
      mu_[mt][j] = mu;
      rs_[mt][j] = 1.f / sqrtf(var + 1e-5f);
    }

#pragma unroll
  for (int mt = 0; mt < 4; mt++)
#pragma unroll
    for (int j = 0; j < 4; j++) {
      int r = m0 + wr * 64 + mt * 16 + l4 * 4 + j;
#pragma unroll
      for (int nt = 0; nt < 4; nt++) {
        int d = wc * 64 + nt * 16 + l15;
        float y = (acc[mt][nt][j] - mu_[mt][j]) * rs_[mt][j] * lw[d] + lb[d];
        if (cb < 32) y *= SCLLOG2E;   // fold softmax scale + log2e into Q/Qx
        uint16_t hb = f16_bits(y);
        if (cb < 16) {
          Qh[((size_t)r * NH_ + cb) * D_ + d] = hb;
        } else if (cb < 32) {
          Qxh[((size_t)r * NH_ + (cb - 16)) * D_ + d] = hb;
        } else {
          Kf[((size_t)r * G_ + (cb - 32)) * D_ + d] = hb;
        }
      }
    }
}

// ---------------- kvx GEMM: m97 structure, split A/B 3-MFMA, BM=64 -----------
__global__ __launch_bounds__(256) void k_kvx(
    const uint16_t* __restrict__ Ah, const uint16_t* __restrict__ Al,
    const uint16_t* __restrict__ Bh, const uint16_t* __restrict__ Bl,
    const float* __restrict__ kxln_w, const float* __restrict__ kxln_b,
    uint16_t* __restrict__ Kxf, uint16_t* __restrict__ Vxtf)
{
  const int K = 2048;
  __shared__ __align__(64) uint8_t smem[26624];
  uint16_t* lA  = (uint16_t*)smem;                 // 64*32*2  = 4096
  uint16_t* lA2 = (uint16_t*)(smem + 4096);        // 4096
  uint16_t* lB  = (uint16_t*)(smem + 8192);        // 128*32*2 = 8192
  uint16_t* lB2 = (uint16_t*)(smem + 16384);       // 8192
  float* sred = (float*)(smem + 24576);
  uint16_t* sT = (uint16_t*)smem;                  // Vx overlay: 128*72*2 = 18432

  const int tid = threadIdx.x;
  const int lane = tid & 63;
  const int wv = tid >> 6;
  const int wc = wv;
  const int l15 = lane & 15, l4 = lane >> 4;
  const int m0 = blockIdx.y * 64, n0 = blockIdx.x * 128;

  const int ar0 = tid >> 2, ag0 = (tid & 3) ^ (ar0 & 3);
  int brow[2], bcg[2];
#pragma unroll
  for (int c = 0; c < 2; c++) {
    int i = c * 256 + tid;
    brow[c] = i >> 2;
    bcg[c] = (i & 3) ^ (brow[c] & 3);
  }
  const int axo = ((l4 ^ (l15 & 3)) * 8);

  f32x4 acc[4][2] = {};

  for (int kt = 0; kt < K; kt += 32) {
    __syncthreads();
    GLOAD_LDS16(&Ah[(size_t)(m0 + ar0) * K + kt + ag0 * 8], &lA[(wv * 64) * 8]);
    GLOAD_LDS16(&Al[(size_t)(m0 + ar0) * K + kt + ag0 * 8], &lA2[(wv * 64) * 8]);
#pragma unroll
    for (int c = 0; c < 2; c++) {
      GLOAD_LDS16(&Bh[(size_t)(n0 + brow[c]) * K + kt + bcg[c] * 8],
                  &lB[(c * 256 + wv * 64) * 8]);
      GLOAD_LDS16(&Bl[(size_t)(n0 + brow[c]) * K + kt + bcg[c] * 8],
                  &lB2[(c * 256 + wv * 64) * 8]);
    }
    __syncthreads();
    bf16x8 af[4], af2[4];
#pragma unroll
    for (int mt = 0; mt < 4; mt++) {
      af[mt]  = *(bf16x8*)&lA[(mt * 16 + l15) * 32 + axo];
      af2[mt] = *(bf16x8*)&lA2[(mt * 16 + l15) * 32 + axo];
    }
#pragma unroll
    for (int nt = 0; nt < 2; nt++) {
      bf16x8 bh = *(bf16x8*)&lB[(wc * 32 + nt * 16 + l15) * 32 + axo];
      bf16x8 bl = *(bf16x8*)&lB2[(wc * 32 + nt * 16 + l15) * 32 + axo];
#pragma unroll
      for (int mt = 0; mt < 4; mt++) {
        acc[mt][nt] = __builtin_amdgcn_mfma_f32_16x16x32_bf16(af[mt], bh, acc[mt][nt], 0, 0, 0);
        acc[mt][nt] = __builtin_amdgcn_mfma_f32_16x16x32_bf16(af[mt], bl, acc[mt][nt], 0, 0, 0);
        acc[mt][nt] = __builtin_amdgcn_mfma_f32_16x16x32_bf16(af2[mt], bh, acc[mt][nt], 0, 0, 0);
      }
    }
  }

  const int cb = n0 >> 7;

  if (cb >= 8) {
    // Vx: transpose through LDS (pad 72 keeps 16B alignment), coalesced stores
    __syncthreads();
#pragma unroll
    for (int mt = 0; mt < 4; mt++)
#pragma unroll
      for (int j = 0; j < 4; j++) {
        int rl = mt * 16 + l4 * 4 + j;
#pragma unroll
        for (int nt = 0; nt < 2; nt++) {
          int d = wc * 32 + nt * 16 + l15;
          sT[d * 72 + rl] = bf16_rne_bits(acc[mt][nt][j]);
        }
      }
    __syncthreads();
    int gg = cb - 8;
    int d = tid >> 1, rh = (tid & 1) << 5;
    size_t gbase = (((size_t)(m0 >> 9) * G_ + gg) * D_ + d) * (size_t)SC_ +
                   (m0 & 511) + rh;
    const uint16_t* sp = &sT[d * 72 + rh];
#pragma unroll
    for (int k = 0; k < 4; k++)
      *(bf16x8*)&Vxtf[gbase + k * 8] = *(const bf16x8*)&sp[k * 8];
    return;
  }

  float mu_[4][4], rs_[4][4];
#pragma unroll
  for (int mt = 0; mt < 4; mt++)
#pragma unroll
    for (int j = 0; j < 4; j++) {
      float s = 0.f, sq = 0.f;
#pragma unroll
      for (int nt = 0; nt < 2; nt++) { float t = acc[mt][nt][j]; s += t; sq += t * t; }
#pragma unroll
      for (int mm = 1; mm < 16; mm <<= 1) { s += __shfl_xor(s, mm); sq += __shfl_xor(sq, mm); }
      if (l15 == 0) {
        int ar = mt * 16 + l4 * 4 + j;
        sred[wc * 64 + ar] = s;
        sred[256 + wc * 64 + ar] = sq;
      }
    }
  __syncthreads();
#pragma unroll
  for (int mt = 0; mt < 4; mt++)
#pragma unroll
    for (int j = 0; j < 4; j++) {
      int ar = mt * 16 + l4 * 4 + j;
      float Sm = sred[ar] + sred[64 + ar] + sred[128 + ar] + sred[192 + ar];
      float Sq = sred[256 + ar] + sred[320 + ar] + sred[384 + ar] + sred[448 + ar];
      float mu = Sm * (1.f / 128.f);
      float var = Sq * (1.f / 128.f) - mu * mu;
      mu_[mt][j] = mu;
      rs_[mt][j] = 1.f / sqrtf(var + 1e-5f);
    }

#pragma unroll
  for (int mt = 0; mt < 4; mt++)
#pragma unroll
    for (int j = 0; j < 4; j++) {
      int r = m0 + mt * 16 + l4 * 4 + j;
#pragma unroll
      for (int nt = 0; nt < 2; nt++) {
        int d = wc * 32 + nt * 16 + l15;
        float y = (acc[mt][nt][j] - mu_[mt][j]) * rs_[mt][j] * kxln_w[d] + kxln_b[d];
        Kxf[((size_t)r * G_ + cb) * D_ + d] = f16_bits(y);
      }
    }
}

// ---------------- merged flash GQA attention (8-wave, QBLK=128, balanced) ----
// z: 0,1 = self (1 q-tile each, T=2048); z: 2,3 = cross (x<4; 4 q-tiles each,
// T=512) -> 640 equal-duration blocks. Single body copy (#pragma unroll 1)
// keeps VGPR at R9's level (<=64 = occupancy-cliff bound).
__global__ __launch_bounds__(512) void k_attn(
    const uint16_t* __restrict__ Qs, const uint16_t* __restrict__ Qx,
    const uint16_t* __restrict__ Ks, const uint16_t* __restrict__ Vs,
    const uint16_t* __restrict__ Kx, const uint16_t* __restrict__ Vx,
    const float* __restrict__ smooth, uint8_t* __restrict__ catq)
{
  __shared__ __align__(16) uint16_t lK[2][32 * 128];   // 16 KB
  __shared__ __align__(16) uint16_t lV[2][128 * 32];   // 16 KB
  __shared__ __align__(16) uint16_t lP[128 * 32];      // 8 KB

  const int tid = threadIdx.x, lane = tid & 63, wv = tid >> 6;  // wv 0..7
  const int l15 = lane & 15, l4 = lane >> 4;
  const int h = blockIdx.y;
  const int zb = blockIdx.z;
  const int b = zb & 1;
  const bool xr = zb >= 2;
  if (xr && blockIdx.x >= 4) return;   // balanced grid: 4 x-slots for cross
  const uint16_t* __restrict__ Q = xr ? Qx : Qs;
  const uint16_t* __restrict__ Kp = xr ? Kx : Ks;
  const uint16_t* __restrict__ Vp = xr ? Vx : Vs;
  const int T = xr ? SC_ : S_;
  const int colOff = xr ? 2048 : 0;
  const int g = h >> 1;

  // staging: 512 threads, 1 chunk (16 B) each for K and V
  const int krow = tid >> 4, kcg = (tid & 15) ^ (krow & 7);
  const int vrow = tid >> 2, vcg = (tid & 3) ^ (vrow & 3);

  // paired-column K mapping: output col l15 of MFMA nt <-> K row t = 2*l15+nt.
  int koff[2][4];
#pragma unroll
  for (int nt = 0; nt < 2; nt++)
#pragma unroll
    for (int ks = 0; ks < 4; ks++) {
      int t = 2 * l15 + nt;
      koff[nt][ks] = t * 128 + (((ks * 4 + l4) ^ (t & 7)) * 8);
    }
  const int vxo = (l4 ^ (l15 & 3)) * 8;

  const f32x4 CINIT = {-FIXED_M, -FIXED_M, -FIXED_M, -FIXED_M};
  const size_t kbase0 = ((size_t)b * T + krow) * (G_ * D_) + (size_t)g * D_ + kcg * 8;
  const size_t vbase0 = (((size_t)b * G_ + g) * (size_t)D_ + vrow) * (size_t)T + vcg * 8;
  const int nT = T >> 5;

  int nq = xr ? 4 : 1;
  int qt0 = xr ? (blockIdx.x * 4) : blockIdx.x;

#pragma unroll 1
  for (int qi = 0; qi < nq; qi++) {
    const int q0 = (qt0 + qi) * 128;

    f16x8 qf[4];
    {
      int srow = q0 + wv * 16 + l15;
      size_t base = (((size_t)b * S_ + srow) * NH_ + h) * (size_t)D_ + l4 * 8;
#pragma unroll
      for (int ks = 0; ks < 4; ks++)
        qf[ks] = *(const f16x8*)&Q[base + ks * 32];
    }

    float lsump[4] = {0.f, 0.f, 0.f, 0.f};
    f32x4 oacc[8] = {};

    const uint16_t* pK = Kp + kbase0;
    const uint16_t* pV = Vp + vbase0;

    // prologue: stage tile 0 into buf 0 (stragglers of previous q-tile read
    // only buf1/lP, and the tt=0 barrier below gates all reuse)
    GLOAD_LDS16(pK, &lK[0][(wv * 64) * 8]);
    GLOAD_LDS16(pV, &lV[0][(wv * 64) * 8]);
    pK += 32 * G_ * D_;
    pV += 32;

    for (int tt = 0; tt < nT; tt++) {
      const int cur = tt & 1;
      __syncthreads();
      if (tt + 1 < nT) {
        GLOAD_LDS16(pK, &lK[cur ^ 1][(wv * 64) * 8]);
        GLOAD_LDS16(pV, &lV[cur ^ 1][(wv * 64) * 8]);
        pK += 32 * G_ * D_;
        pV += 32;
      }

      f32x4 sf[2];
      __builtin_amdgcn_s_setprio(1);
#pragma unroll
      for (int nt = 0; nt < 2; nt++) {
        f16x8 kf0 = *(f16x8*)&lK[cur][koff[nt][0]];
        f32x4 a = __builtin_amdgcn_mfma_f32_16x16x32_f16(qf[0], kf0, CINIT, 0, 0, 0);
#pragma unroll
        for (int ks = 1; ks < 4; ks++) {
          f16x8 kf = *(f16x8*)&lK[cur][koff[nt][ks]];
          a = __builtin_amdgcn_mfma_f32_16x16x32_f16(qf[ks], kf, a, 0, 0, 0);
        }
        sf[nt] = a;
      }
      __builtin_amdgcn_s_setprio(0);

      // branchless softmax: p = exp2(s - M), M folded into MFMA C-init
#pragma unroll
      for (int j = 0; j < 4; j++) {
        float p0 = __builtin_amdgcn_exp2f(sf[0][j]);
        float p1 = __builtin_amdgcn_exp2f(sf[1][j]);
        lsump[j] += p0 + p1;
        int prow = wv * 16 + l4 * 4 + j;
        uint32_t pk;
        asm("v_cvt_pk_bf16_f32 %0, %1, %2" : "=v"(pk) : "v"(p0), "v"(p1));
        *(uint32_t*)&lP[prow * 32 + l15 * 2] = pk;   // cols 2*l15, 2*l15+1
      }

      bf16x8 pa = *(bf16x8*)&lP[(wv * 16 + l15) * 32 + l4 * 8];
      __builtin_amdgcn_s_setprio(1);
#pragma unroll
      for (int dt = 0; dt < 8; dt++) {
        bf16x8 vh = *(bf16x8*)&lV[cur][(dt * 16 + l15) * 32 + vxo];
        oacc[dt] = __builtin_amdgcn_mfma_f32_16x16x32_bf16(pa, vh, oacc[dt], 0, 0, 0);
      }
      __builtin_amdgcn_s_setprio(0);
    }

#pragma unroll
    for (int j = 0; j < 4; j++) {
      float rsum = lsump[j];
#pragma unroll
      for (int mm = 1; mm < 16; mm <<= 1) rsum += __shfl_xor(rsum, mm);
      float inv = 1.f / rsum;
      int srow = q0 + wv * 16 + l4 * 4 + j;
      size_t rbase = ((size_t)b * S_ + srow) * 4096;
#pragma unroll
      for (int dt = 0; dt < 8; dt++) {
        int c = colOff + h * D_ + dt * 16 + l15;
        float t = (oacc[dt][j] * inv) / smooth[c];
        t = fminf(fmaxf(t, -448.f), 448.f);
        t = fp8_rt(bf16_rne_f(t));
        catq[rbase + c] = fp8_enc(t);
      }
    }
    __syncthreads();   // all waves done with lP/buffers before next prologue
  }
}

// ---------------------------------------------------------------------------
extern "C" void kernel_launch(void* const* d_in, const int* in_sizes, int n_in,
                              void* d_out, int out_size, void* d_ws, size_t ws_size,
                              hipStream_t stream)
{
  (void)in_sizes; (void)n_in; (void)out_size;
  const float* hidden = (const float*)d_in[0];
  const float* cond   = (const float*)d_in[1];
  const float* ln_w   = (const float*)d_in[2];
  const float* ln_b   = (const float*)d_in[3];
  const float* wq     = (const float*)d_in[4];
  const float* wq_s   = (const float*)d_in[5];
  const float* q_is   = (const float*)d_in[6];
  const float* wqx    = (const float*)d_in[7];
  const float* wqx_s  = (const float*)d_in[8];
  const float* qx_is  = (const float*)d_in[9];
  const float* wk     = (const float*)d_in[10];
  const float* wk_s   = (const float*)d_in[11];
  const float* k_is   = (const float*)d_in[12];
  const float* wv     = (const float*)d_in[13];
  const float* wv_s   = (const float*)d_in[14];
  const float* v_is   = (const float*)d_in[15];
  const float* wkvx   = (const float*)d_in[16];
  const float* qln_w  = (const float*)d_in[17];
  const float* qln_b  = (const float*)d_in[18];
  const float* kln_w  = (const float*)d_in[19];
  const float* kln_b  = (const float*)d_in[20];
  const float* qxln_w = (const float*)d_in[21];
  const float* qxln_b = (const float*)d_in[22];
  const float* kxln_w = (const float*)d_in[23];
  const float* kxln_b = (const float*)d_in[24];
  const float* wproj  = (const float*)d_in[25];
  const float* p_ws   = (const float*)d_in[26];
  const float* p_is   = (const float*)d_in[27];
  const float* smooth = (const float*)d_in[28];

  char* ws = (char*)d_ws;
  size_t off = 0;
  auto alloc = [&](size_t bytes) {
    char* p = ws + off;
    off += (bytes + 255) & ~(size_t)255;
    return p;
  };
  uint8_t*  Aq    = (uint8_t*)alloc((size_t)4096 * 2048);
  uint8_t*  Wcat  = (uint8_t*)alloc((size_t)6144 * 2048);
  uint8_t*  Wpb   = (uint8_t*)alloc((size_t)2048 * 4096);
  uint16_t* Wkvxh = (uint16_t*)alloc((size_t)2048 * 2048 * 2);
  uint16_t* Wkvxl = (uint16_t*)alloc((size_t)2048 * 2048 * 2);
  uint16_t* condh = (uint16_t*)alloc((size_t)1024 * 2048 * 2);
  uint16_t* condl = (uint16_t*)alloc((size_t)1024 * 2048 * 2);
  uint16_t* Qh    = (uint16_t*)alloc((size_t)4096 * 16 * 128 * 2);
  uint16_t* Qxh   = (uint16_t*)alloc((size_t)4096 * 16 * 128 * 2);
  uint16_t* Kf    = (uint16_t*)alloc((size_t)4096 * 8 * 128 * 2);
  uint16_t* Vtf   = (uint16_t*)alloc((size_t)4096 * 8 * 128 * 2);
  uint16_t* Kxf   = (uint16_t*)alloc((size_t)1024 * 8 * 128 * 2);
  uint16_t* Vxtf  = (uint16_t*)alloc((size_t)1024 * 8 * 128 * 2);
  uint8_t*  catq  = (uint8_t*)alloc((size_t)4096 * 4096);
  float* scales   = (float*)alloc(256);
  if (ws_size < off) return;

  k_prep<<<2048, 256, 0, stream>>>(wq, wqx, wk, wv, wkvx, wproj, cond,
      q_is, wq_s, qx_is, wqx_s, k_is, wk_s, v_is, wv_s, p_is, p_ws,
      Wcat, Wpb, Wkvxh, Wkvxl, condh, condl, scales);

  k_ln_quant<<<4096, 256, 0, stream>>>(hidden, ln_w, ln_b, q_is, Aq);

  k_gemm8<0><<<dim3(48, 32), 256, 0, stream>>>(Aq, Wcat,
      4096, 6144, 2048, scales, qln_w, qln_b, kln_w, kln_b, qxln_w, qxln_b,
      Qh, Qxh, Kf, Vtf, nullptr);

  k_kvx<<<dim3(16, 16), 256, 0, stream>>>(condh, condl, Wkvxh, Wkvxl,
      kxln_w, kxln_b, Kxf, Vxtf);

  k_attn<<<dim3(16, 16, 4), 512, 0, stream>>>(Qh, Qxh, Kf, Vtf, Kxf, Vxtf,
      smooth, catq);

  k_gemm8<2><<<dim3(16, 32), 256, 0, stream>>>(catq, Wpb,
      4096, 2048, 4096, scales, nullptr, nullptr, nullptr, nullptr, nullptr, nullptr,
      nullptr, nullptr, nullptr, nullptr,
      (float*)d_out);
}

// Round 15
// 375.498 us; speedup vs baseline: 1.8082x; 1.2676x over previous
//
#include <hip/hip_runtime.h>
#include <hip/hip_bf16.h>
#include <stdint.h>

#define B_  2
#define S_  2048
#define SC_ 512
#define H_  2048
#define NH_ 16
#define G_  8
#define D_  128

typedef __attribute__((ext_vector_type(8))) short bf16x8;
typedef __attribute__((ext_vector_type(8))) _Float16 f16x8;
typedef __attribute__((ext_vector_type(4))) float f32x4;
typedef __attribute__((ext_vector_type(8))) int i32x8;

// SCL * log2(e) = (1/sqrt(128)) * 1.4426950408889634
#define SCLLOG2E 0.12751741f
// |score_log2| <= SCLLOG2E * ||q|| * ||k|| = SCLLOG2E*128 = 16.3222 (LN => unit rows)
#define FIXED_M  16.34f

#define GLOAD_LDS16(g, l) __builtin_amdgcn_global_load_lds( \
    (const __attribute__((address_space(1))) uint32_t*)(g), \
    (__attribute__((address_space(3))) uint32_t*)(l), 16, 0, 0)

__device__ __forceinline__ uint16_t bf16_rne_bits(float x) {
  uint32_t u = __float_as_uint(x);
  u += 0x7fffu + ((u >> 16) & 1u);
  return (uint16_t)(u >> 16);
}
__device__ __forceinline__ float bf16_rne_f(float x) {
  uint32_t u = __float_as_uint(x);
  u += 0x7fffu + ((u >> 16) & 1u);
  return __uint_as_float(u & 0xffff0000u);
}
__device__ __forceinline__ uint16_t f16_bits(float x) {
  _Float16 h = (_Float16)x;
  return __builtin_bit_cast(uint16_t, h);
}
// fp8 e4m3fn round-trip (RNE, input already clipped to [-448,448])
__device__ __forceinline__ float fp8_rt(float x) {
  float a = fabsf(x);
  float step;
  if (a >= 0.015625f) {
    uint32_t u = __float_as_uint(a);
    int E = (int)((u >> 23) & 0xffu) - 127;
    step = __uint_as_float((uint32_t)(E - 3 + 127) << 23);
  } else {
    step = 0.001953125f;
  }
  float q = rintf(a / step) * step;
  return x < 0.f ? -q : q;
}
// exact e4m3fn encode of a value that is already an exact fp8 value
__device__ __forceinline__ uint8_t fp8_enc(float v) {
  uint32_t u = __float_as_uint(v);
  uint8_t s = (uint8_t)((u >> 24) & 0x80u);
  float a = fabsf(v);
  if (a == 0.f) return s;
  int E = (int)((u >> 23) & 0xffu) - 127;
  if (E < -6) return s | (uint8_t)(a * 512.f);        // subnormal: k * 2^-9
  uint32_t mant = (u >> 20) & 7u;
  return s | ((uint8_t)(E + 7) << 3) | (uint8_t)mant;
}

// ---------------- prep: weight encodes / splits / scalar scales --------------
__global__ __launch_bounds__(256) void k_prep(
    const float* __restrict__ wq, const float* __restrict__ wqx,
    const float* __restrict__ wk, const float* __restrict__ wv,
    const float* __restrict__ wkvx, const float* __restrict__ wproj,
    const float* __restrict__ cond,
    const float* __restrict__ q_is, const float* __restrict__ wq_s,
    const float* __restrict__ qx_is, const float* __restrict__ wqx_s,
    const float* __restrict__ k_is, const float* __restrict__ wk_s,
    const float* __restrict__ v_is, const float* __restrict__ wv_s,
    const float* __restrict__ p_is, const float* __restrict__ p_ws,
    uint8_t* __restrict__ Wcat, uint8_t* __restrict__ Wpb,
    uint16_t* __restrict__ Wkvxh, uint16_t* __restrict__ Wkvxl,
    uint16_t* __restrict__ condh, uint16_t* __restrict__ condl,
    float* __restrict__ scales)
{
  size_t idx = (size_t)blockIdx.x * 256 + threadIdx.x;
  size_t stride = (size_t)gridDim.x * 256;
  const size_t NC = (size_t)6144 * 2048;
  for (size_t i = idx; i < NC; i += stride) {
    size_t row = i >> 11; int col = (int)(i & 2047);
    float v;
    if (row < 2048)      v = wq[i];
    else if (row < 4096) v = wqx[(row - 2048) * 2048 + col];
    else if (row < 5120) v = wk[(row - 4096) * 2048 + col];
    else                 v = wv[(row - 5120) * 2048 + col];
    Wcat[i] = fp8_enc(v);
  }
  const size_t NP = (size_t)2048 * 4096;
  for (size_t i = idx; i < NP; i += stride)
    Wpb[i] = fp8_enc(wproj[i]);
  const size_t NX = (size_t)2048 * 2048;
  for (size_t i = idx; i < NX; i += stride) {
    float x = wkvx[i];
    uint16_t h = bf16_rne_bits(x);
    Wkvxh[i] = h;
    Wkvxl[i] = bf16_rne_bits(x - __uint_as_float((uint32_t)h << 16));
  }
  const size_t ND = (size_t)1024 * 2048;
  for (size_t i = idx; i < ND; i += stride) {
    float x = cond[i];
    uint16_t h = bf16_rne_bits(x);
    condh[i] = h;
    condl[i] = bf16_rne_bits(x - __uint_as_float((uint32_t)h << 16));
  }
  if (idx == 0) {
    scales[0] = q_is[0] * wq_s[0];
    scales[1] = qx_is[0] * wqx_s[0];
    scales[2] = k_is[0] * wk_s[0];
    scales[3] = v_is[0] * wv_s[0];
    scales[4] = p_is[0] * p_ws[0];
  }
}

// ---------------- hidden LayerNorm + fp8 quantize -> Aq (fp8 bytes) ----------
__global__ __launch_bounds__(256) void k_ln_quant(
    const float* __restrict__ x, const float* __restrict__ w,
    const float* __restrict__ b, const float* __restrict__ qis,
    uint8_t* __restrict__ Aq)
{
  int row = blockIdx.x;
  int tid = threadIdx.x;
  const float* xr = x + (size_t)row * H_;
  float v[8];
  float s = 0.f, sq = 0.f;
#pragma unroll
  for (int i = 0; i < 8; i++) {
    float t = xr[tid + i * 256];
    v[i] = t; s += t; sq += t * t;
  }
#pragma unroll
  for (int m = 1; m < 64; m <<= 1) { s += __shfl_xor(s, m); sq += __shfl_xor(sq, m); }
  __shared__ float red[8];
  int wv = tid >> 6;
  if ((tid & 63) == 0) { red[wv] = s; red[4 + wv] = sq; }
  __syncthreads();
  s = red[0] + red[1] + red[2] + red[3];
  sq = red[4] + red[5] + red[6] + red[7];
  float mu = s * (1.f / H_);
  float var = sq * (1.f / H_) - mu * mu;
  float rs = 1.0f / sqrtf(var + 1e-5f);
#pragma unroll
  for (int i = 0; i < 8; i++) {
    int c = tid + i * 256;
    float y = (v[i] - mu) * rs * w[c] + b[c];
    float t = y / qis[c];
    t = fminf(fmaxf(t, -448.f), 448.f);
    t = fp8_rt(bf16_rne_f(t));
    Aq[(size_t)row * H_ + c] = fp8_enc(t);
  }
}

// ---------------- MX-fp8 GEMM (B^T layout), K-step = 128 fp8 bytes -----------
// MODE 0: QKV proj -> per-head LN -> Q/Qx pre-scaled f16, K f16, V^T bf16
// MODE 2: out proj -> *scale -> f32 out
template <int MODE>
__global__ __launch_bounds__(256) void k_gemm8(
    const uint8_t* __restrict__ A, const uint8_t* __restrict__ Bm,
    int M, int N, int K,
    const float* __restrict__ scales,
    const float* __restrict__ qln_w, const float* __restrict__ qln_b,
    const float* __restrict__ kln_w, const float* __restrict__ kln_b,
    const float* __restrict__ qxln_w, const float* __restrict__ qxln_b,
    uint16_t* __restrict__ Qh,
    uint16_t* __restrict__ Qxh,
    uint16_t* __restrict__ Kf, uint16_t* __restrict__ Vtf,
    float* __restrict__ Cout)
{
  __shared__ __align__(64) uint8_t smem[128 * 136 * 2];  // >= 32768+2048 staging+sred
  uint8_t* lA = smem;
  uint8_t* lB = smem + 128 * 128;
  float* sred = (float*)(smem + 128 * 128 * 2);
  uint16_t* sT = (uint16_t*)smem;          // V-path overlay: 128*136*2 = 34816 B

  const int tid = threadIdx.x;
  const int lane = tid & 63;
  const int wv = tid >> 6;
  const int wr = wv >> 1, wc = wv & 1;
  const int l15 = lane & 15, l4 = lane >> 4;
  const int m0 = blockIdx.y * 128, n0 = blockIdx.x * 128;

  int srow[4]; int soff[4];
#pragma unroll
  for (int c = 0; c < 4; c++) {
    int i = c * 256 + tid;
    int row = i >> 3, s = i & 7;
    srow[c] = row;
    soff[c] = (((s >> 1) ^ (row & 3)) << 5) + ((s & 1) << 4);
  }
  const int axo = ((l4 ^ (l15 & 3)) << 5);

  f32x4 acc[4][4] = {};

  for (int kt = 0; kt < K; kt += 128) {
    __syncthreads();
#pragma unroll
    for (int c = 0; c < 4; c++) {
      GLOAD_LDS16(&A[(size_t)(m0 + srow[c]) * K + kt + soff[c]],
                  &lA[(c * 256 + wv * 64) * 16]);
      GLOAD_LDS16(&Bm[(size_t)(n0 + srow[c]) * K + kt + soff[c]],
                  &lB[(c * 256 + wv * 64) * 16]);
    }
    __syncthreads();
    i32x8 af[4];
#pragma unroll
    for (int mt = 0; mt < 4; mt++)
      af[mt] = *(i32x8*)&lA[(wr * 64 + mt * 16 + l15) * 128 + axo];
#pragma unroll
    for (int nt = 0; nt < 4; nt++) {
      i32x8 bf = *(i32x8*)&lB[(wc * 64 + nt * 16 + l15) * 128 + axo];
#pragma unroll
      for (int mt = 0; mt < 4; mt++)
        acc[mt][nt] = __builtin_amdgcn_mfma_scale_f32_16x16x128_f8f6f4(
            af[mt], bf, acc[mt][nt], 0, 0, 0, 0x7F7F7F7F, 0, 0x7F7F7F7F);
    }
  }

  const int cb = n0 >> 7;
  float sscale;
  const float *lw = nullptr, *lb = nullptr;
  if (MODE == 0) {
    int sect = (cb < 16) ? 0 : (cb < 32) ? 1 : (cb < 40) ? 2 : 3;
    sscale = scales[sect];
    if (sect == 0) { lw = qln_w; lb = qln_b; }
    else if (sect == 1) { lw = qxln_w; lb = qxln_b; }
    else if (sect == 2) { lw = kln_w; lb = kln_b; }
  } else {
    sscale = scales[4];
  }
#pragma unroll
  for (int mt = 0; mt < 4; mt++)
#pragma unroll
    for (int nt = 0; nt < 4; nt++)
#pragma unroll
      for (int j = 0; j < 4; j++) acc[mt][nt][j] *= sscale;

  if (MODE == 2) {
#pragma unroll
    for (int mt = 0; mt < 4; mt++)
#pragma unroll
      for (int j = 0; j < 4; j++) {
        int r = m0 + wr * 64 + mt * 16 + l4 * 4 + j;
#pragma unroll
        for (int nt = 0; nt < 4; nt++) {
          int c = n0 + wc * 64 + nt * 16 + l15;
          Cout[(size_t)r * N + c] = acc[mt][nt][j];
        }
      }
    return;
  }

  if (MODE == 0 && cb >= 40) {
    // V section: transpose through LDS, coalesced bf16 stores.
    __syncthreads();   // staging LDS no longer needed; safe to overlay
#pragma unroll
    for (int mt = 0; mt < 4; mt++)
#pragma unroll
      for (int j = 0; j < 4; j++) {
        int rl = wr * 64 + mt * 16 + l4 * 4 + j;
#pragma unroll
        for (int nt = 0; nt < 4; nt++) {
          int d = wc * 64 + nt * 16 + l15;
          sT[d * 136 + rl] = bf16_rne_bits(acc[mt][nt][j]);
        }
      }
    __syncthreads();
    int gg = cb - 40;
    int d = tid >> 1, rh = (tid & 1) << 6;
    size_t gbase = (((size_t)(m0 >> 11) * G_ + gg) * D_ + d) * (size_t)S_ +
                   (m0 & 2047) + rh;
    const uint16_t* sp = &sT[d * 136 + rh];
#pragma unroll
    for (int k = 0; k < 8; k++)
      *(bf16x8*)&Vtf[gbase + k * 8] = *(const bf16x8*)&sp[k * 8];
    return;
  }

  // Q / Qx / K sections: per-head LN over the 128-col tile
  float mu_[4][4], rs_[4][4];
#pragma unroll
  for (int mt = 0; mt < 4; mt++)
#pragma unroll
    for (int j = 0; j < 4; j++) {
      float s = 0.f, sq = 0.f;
#pragma unroll
      for (int nt = 0; nt < 4; nt++) { float t = acc[mt][nt][j]; s += t; sq += t * t; }
#pragma unroll
      for (int mm = 1; mm < 16; mm <<= 1) { s += __shfl_xor(s, mm); sq += __shfl_xor(sq, mm); }
      if (l15 == 0) {
        int ar = wr * 64 + mt * 16 + l4 * 4 + j;
        sred[wc * 128 + ar] = s;
        sred[256 + wc * 128 + ar] = sq;
      }
    }
  __syncthreads();
#pragma unroll
  for (int mt = 0; mt < 4; mt++)
#pragma unroll
    for (int j = 0; j < 4; j++) {
      int ar = wr * 64 + mt * 16 + l4 * 4 + j;
      float Sm = sred[ar] + sred[128 + ar];
      float Sq = sred[256 + ar] + sred[384 + ar];
      float mu = Sm * (1.f / 128.f);
      float var = Sq * (1.f / 128.f) - mu * mu;
      mu_[mt][j] = mu;
      rs_[mt][j] = 1.f / sqrtf(var + 1e-5f);
    }

#pragma unroll
  for (int mt = 0; mt < 4; mt++)
#pragma unroll
    for (int j = 0; j < 4; j++) {
      int r = m0 + wr * 64 + mt * 16 + l4 * 4 + j;
#pragma unroll
      for (int nt = 0; nt < 4; nt++) {
        int d = wc * 64 + nt * 16 + l15;
        float y = (acc[mt][nt][j] - mu_[mt][j]) * rs_[mt][j] * lw[d] + lb[d];
        if (cb < 32) y *= SCLLOG2E;   // fold softmax scale + log2e into Q/Qx
        uint16_t hb = f16_bits(y);
        if (cb < 16) {
          Qh[((size_t)r * NH_ + cb) * D_ + d] = hb;
        } else if (cb < 32) {
          Qxh[((size_t)r * NH_ + (cb - 16)) * D_ + d] = hb;
        } else {
          Kf[((size_t)r * G_ + (cb - 32)) * D_ + d] = hb;
        }
      }
    }
}

// ---------------- kvx GEMM: m97 structure, split A/B 3-MFMA, BM=64 -----------
__global__ __launch_bounds__(256) void k_kvx(
    const uint16_t* __restrict__ Ah, const uint16_t* __restrict__ Al,
    const uint16_t* __restrict__ Bh, const uint16_t* __restrict__ Bl,
    const float* __restrict__ kxln_w, const float* __restrict__ kxln_b,
    uint16_t* __restrict__ Kxf, uint16_t* __restrict__ Vxtf)
{
  const int K = 2048;
  __shared__ __align__(64) uint8_t smem[26624];
  uint16_t* lA  = (uint16_t*)smem;                 // 64*32*2  = 4096
  uint16_t* lA2 = (uint16_t*)(smem + 4096);        // 4096
  uint16_t* lB  = (uint16_t*)(smem + 8192);        // 128*32*2 = 8192
  uint16_t* lB2 = (uint16_t*)(smem + 16384);       // 8192
  float* sred = (float*)(smem + 24576);
  uint16_t* sT = (uint16_t*)smem;                  // Vx overlay: 128*72*2 = 18432

  const int tid = threadIdx.x;
  const int lane = tid & 63;
  const int wv = tid >> 6;
  const int wc = wv;
  const int l15 = lane & 15, l4 = lane >> 4;
  const int m0 = blockIdx.y * 64, n0 = blockIdx.x * 128;

  const int ar0 = tid >> 2, ag0 = (tid & 3) ^ (ar0 & 3);
  int brow[2], bcg[2];
#pragma unroll
  for (int c = 0; c < 2; c++) {
    int i = c * 256 + tid;
    brow[c] = i >> 2;
    bcg[c] = (i & 3) ^ (brow[c] & 3);
  }
  const int axo = ((l4 ^ (l15 & 3)) * 8);

  f32x4 acc[4][2] = {};

  for (int kt = 0; kt < K; kt += 32) {
    __syncthreads();
    GLOAD_LDS16(&Ah[(size_t)(m0 + ar0) * K + kt + ag0 * 8], &lA[(wv * 64) * 8]);
    GLOAD_LDS16(&Al[(size_t)(m0 + ar0) * K + kt + ag0 * 8], &lA2[(wv * 64) * 8]);
#pragma unroll
    for (int c = 0; c < 2; c++) {
      GLOAD_LDS16(&Bh[(size_t)(n0 + brow[c]) * K + kt + bcg[c] * 8],
                  &lB[(c * 256 + wv * 64) * 8]);
      GLOAD_LDS16(&Bl[(size_t)(n0 + brow[c]) * K + kt + bcg[c] * 8],
                  &lB2[(c * 256 + wv * 64) * 8]);
    }
    __syncthreads();
    bf16x8 af[4], af2[4];
#pragma unroll
    for (int mt = 0; mt < 4; mt++) {
      af[mt]  = *(bf16x8*)&lA[(mt * 16 + l15) * 32 + axo];
      af2[mt] = *(bf16x8*)&lA2[(mt * 16 + l15) * 32 + axo];
    }
#pragma unroll
    for (int nt = 0; nt < 2; nt++) {
      bf16x8 bh = *(bf16x8*)&lB[(wc * 32 + nt * 16 + l15) * 32 + axo];
      bf16x8 bl = *(bf16x8*)&lB2[(wc * 32 + nt * 16 + l15) * 32 + axo];
#pragma unroll
      for (int mt = 0; mt < 4; mt++) {
        acc[mt][nt] = __builtin_amdgcn_mfma_f32_16x16x32_bf16(af[mt], bh, acc[mt][nt], 0, 0, 0);
        acc[mt][nt] = __builtin_amdgcn_mfma_f32_16x16x32_bf16(af[mt], bl, acc[mt][nt], 0, 0, 0);
        acc[mt][nt] = __builtin_amdgcn_mfma_f32_16x16x32_bf16(af2[mt], bh, acc[mt][nt], 0, 0, 0);
      }
    }
  }

  const int cb = n0 >> 7;

  if (cb >= 8) {
    // Vx: transpose through LDS (pad 72 keeps 16B alignment), coalesced stores
    __syncthreads();
#pragma unroll
    for (int mt = 0; mt < 4; mt++)
#pragma unroll
      for (int j = 0; j < 4; j++) {
        int rl = mt * 16 + l4 * 4 + j;
#pragma unroll
        for (int nt = 0; nt < 2; nt++) {
          int d = wc * 32 + nt * 16 + l15;
          sT[d * 72 + rl] = bf16_rne_bits(acc[mt][nt][j]);
        }
      }
    __syncthreads();
    int gg = cb - 8;
    int d = tid >> 1, rh = (tid & 1) << 5;
    size_t gbase = (((size_t)(m0 >> 9) * G_ + gg) * D_ + d) * (size_t)SC_ +
                   (m0 & 511) + rh;
    const uint16_t* sp = &sT[d * 72 + rh];
#pragma unroll
    for (int k = 0; k < 4; k++)
      *(bf16x8*)&Vxtf[gbase + k * 8] = *(const bf16x8*)&sp[k * 8];
    return;
  }

  float mu_[4][4], rs_[4][4];
#pragma unroll
  for (int mt = 0; mt < 4; mt++)
#pragma unroll
    for (int j = 0; j < 4; j++) {
      float s = 0.f, sq = 0.f;
#pragma unroll
      for (int nt = 0; nt < 2; nt++) { float t = acc[mt][nt][j]; s += t; sq += t * t; }
#pragma unroll
      for (int mm = 1; mm < 16; mm <<= 1) { s += __shfl_xor(s, mm); sq += __shfl_xor(sq, mm); }
      if (l15 == 0) {
        int ar = mt * 16 + l4 * 4 + j;
        sred[wc * 64 + ar] = s;
        sred[256 + wc * 64 + ar] = sq;
      }
    }
  __syncthreads();
#pragma unroll
  for (int mt = 0; mt < 4; mt++)
#pragma unroll
    for (int j = 0; j < 4; j++) {
      int ar = mt * 16 + l4 * 4 + j;
      float Sm = sred[ar] + sred[64 + ar] + sred[128 + ar] + sred[192 + ar];
      float Sq = sred[256 + ar] + sred[320 + ar] + sred[384 + ar] + sred[448 + ar];
      float mu = Sm * (1.f / 128.f);
      float var = Sq * (1.f / 128.f) - mu * mu;
      mu_[mt][j] = mu;
      rs_[mt][j] = 1.f / sqrtf(var + 1e-5f);
    }

#pragma unroll
  for (int mt = 0; mt < 4; mt++)
#pragma unroll
    for (int j = 0; j < 4; j++) {
      int r = m0 + mt * 16 + l4 * 4 + j;
#pragma unroll
      for (int nt = 0; nt < 2; nt++) {
        int d = wc * 32 + nt * 16 + l15;
        float y = (acc[mt][nt][j] - mu_[mt][j]) * rs_[mt][j] * kxln_w[d] + kxln_b[d];
        Kxf[((size_t)r * G_ + cb) * D_ + d] = f16_bits(y);
      }
    }
}

// ---------------- merged flash GQA attention (8-wave, QBLK=128) --------------
// R9-exact (measured optimum: 176-178 us, 48 VGPR, absmax 0.005127).
// z: 0,1 self; 2,3 cross. Q pre-scaled by SCL*log2e; fixed max via MFMA
// C-init (LN => |score_log2| <= 16.33); P,V in bf16.
__global__ __launch_bounds__(512) void k_attn(
    const uint16_t* __restrict__ Qs, const uint16_t* __restrict__ Qx,
    const uint16_t* __restrict__ Ks, const uint16_t* __restrict__ Vs,
    const uint16_t* __restrict__ Kx, const uint16_t* __restrict__ Vx,
    const float* __restrict__ smooth, uint8_t* __restrict__ catq)
{
  __shared__ __align__(16) uint16_t lK[2][32 * 128];   // 16 KB
  __shared__ __align__(16) uint16_t lV[2][128 * 32];   // 16 KB
  __shared__ __align__(16) uint16_t lP[128 * 32];      // 8 KB

  const int tid = threadIdx.x, lane = tid & 63, wv = tid >> 6;  // wv 0..7
  const int l15 = lane & 15, l4 = lane >> 4;
  const int q0 = blockIdx.x * 128, h = blockIdx.y;
  const int zb = blockIdx.z;
  const int b = zb & 1;
  const bool xr = zb >= 2;
  const uint16_t* __restrict__ Q = xr ? Qx : Qs;
  const uint16_t* __restrict__ Kp = xr ? Kx : Ks;
  const uint16_t* __restrict__ Vp = xr ? Vx : Vs;
  const int T = xr ? SC_ : S_;
  const int colOff = xr ? 2048 : 0;
  const int g = h >> 1;

  f16x8 qf[4];
  {
    int srow = q0 + wv * 16 + l15;
    size_t base = (((size_t)b * S_ + srow) * NH_ + h) * (size_t)D_ + l4 * 8;
#pragma unroll
    for (int ks = 0; ks < 4; ks++)
      qf[ks] = *(const f16x8*)&Q[base + ks * 32];
  }

  // staging: 512 threads, 1 chunk (16 B) each for K and V
  const int krow = tid >> 4, kcg = (tid & 15) ^ (krow & 7);
  const int vrow = tid >> 2, vcg = (tid & 3) ^ (vrow & 3);

  // paired-column K mapping: output col l15 of MFMA nt <-> K row t = 2*l15+nt.
  int koff[2][4];
#pragma unroll
  for (int nt = 0; nt < 2; nt++)
#pragma unroll
    for (int ks = 0; ks < 4; ks++) {
      int t = 2 * l15 + nt;
      koff[nt][ks] = t * 128 + (((ks * 4 + l4) ^ (t & 7)) * 8);
    }
  const int vxo = (l4 ^ (l15 & 3)) * 8;

  const f32x4 CINIT = {-FIXED_M, -FIXED_M, -FIXED_M, -FIXED_M};
  float lsump[4] = {0.f, 0.f, 0.f, 0.f};
  f32x4 oacc[8] = {};

  const uint16_t* pK = Kp + ((size_t)b * T + krow) * (G_ * D_) + (size_t)g * D_ + kcg * 8;
  const uint16_t* pV = Vp + (((size_t)b * G_ + g) * (size_t)D_ + vrow) * (size_t)T + vcg * 8;

  // prologue: stage tile 0 into buf 0
  GLOAD_LDS16(pK, &lK[0][(wv * 64) * 8]);
  GLOAD_LDS16(pV, &lV[0][(wv * 64) * 8]);
  pK += 32 * G_ * D_;
  pV += 32;

  const int nT = T >> 5;
  for (int tt = 0; tt < nT; tt++) {
    const int cur = tt & 1;
    __syncthreads();
    if (tt + 1 < nT) {
      GLOAD_LDS16(pK, &lK[cur ^ 1][(wv * 64) * 8]);
      GLOAD_LDS16(pV, &lV[cur ^ 1][(wv * 64) * 8]);
      pK += 32 * G_ * D_;
      pV += 32;
    }

    f32x4 sf[2];
    __builtin_amdgcn_s_setprio(1);
#pragma unroll
    for (int nt = 0; nt < 2; nt++) {
      f16x8 kf0 = *(f16x8*)&lK[cur][koff[nt][0]];
      f32x4 a = __builtin_amdgcn_mfma_f32_16x16x32_f16(qf[0], kf0, CINIT, 0, 0, 0);
#pragma unroll
      for (int ks = 1; ks < 4; ks++) {
        f16x8 kf = *(f16x8*)&lK[cur][koff[nt][ks]];
        a = __builtin_amdgcn_mfma_f32_16x16x32_f16(qf[ks], kf, a, 0, 0, 0);
      }
      sf[nt] = a;
    }
    __builtin_amdgcn_s_setprio(0);

    // branchless softmax: p = exp2(s - M), M folded into MFMA C-init
#pragma unroll
    for (int j = 0; j < 4; j++) {
      float p0 = __builtin_amdgcn_exp2f(sf[0][j]);
      float p1 = __builtin_amdgcn_exp2f(sf[1][j]);
      lsump[j] += p0 + p1;
      int prow = wv * 16 + l4 * 4 + j;
      uint32_t pk;
      asm("v_cvt_pk_bf16_f32 %0, %1, %2" : "=v"(pk) : "v"(p0), "v"(p1));
      *(uint32_t*)&lP[prow * 32 + l15 * 2] = pk;   // cols 2*l15, 2*l15+1
    }

    bf16x8 pa = *(bf16x8*)&lP[(wv * 16 + l15) * 32 + l4 * 8];
    __builtin_amdgcn_s_setprio(1);
#pragma unroll
    for (int dt = 0; dt < 8; dt++) {
      bf16x8 vh = *(bf16x8*)&lV[cur][(dt * 16 + l15) * 32 + vxo];
      oacc[dt] = __builtin_amdgcn_mfma_f32_16x16x32_bf16(pa, vh, oacc[dt], 0, 0, 0);
    }
    __builtin_amdgcn_s_setprio(0);
  }

#pragma unroll
  for (int j = 0; j < 4; j++) {
    float rsum = lsump[j];
#pragma unroll
    for (int mm = 1; mm < 16; mm <<= 1) rsum += __shfl_xor(rsum, mm);
    float inv = 1.f / rsum;
    int srow = q0 + wv * 16 + l4 * 4 + j;
    size_t rbase = ((size_t)b * S_ + srow) * 4096;
#pragma unroll
    for (int dt = 0; dt < 8; dt++) {
      int c = colOff + h * D_ + dt * 16 + l15;
      float t = (oacc[dt][j] * inv) / smooth[c];
      t = fminf(fmaxf(t, -448.f), 448.f);
      t = fp8_rt(bf16_rne_f(t));
      catq[rbase + c] = fp8_enc(t);
    }
  }
}

// ---------------------------------------------------------------------------
extern "C" void kernel_launch(void* const* d_in, const int* in_sizes, int n_in,
                              void* d_out, int out_size, void* d_ws, size_t ws_size,
                              hipStream_t stream)
{
  (void)in_sizes; (void)n_in; (void)out_size;
  const float* hidden = (const float*)d_in[0];
  const float* cond   = (const float*)d_in[1];
  const float* ln_w   = (const float*)d_in[2];
  const float* ln_b   = (const float*)d_in[3];
  const float* wq     = (const float*)d_in[4];
  const float* wq_s   = (const float*)d_in[5];
  const float* q_is   = (const float*)d_in[6];
  const float* wqx    = (const float*)d_in[7];
  const float* wqx_s  = (const float*)d_in[8];
  const float* qx_is  = (const float*)d_in[9];
  const float* wk     = (const float*)d_in[10];
  const float* wk_s   = (const float*)d_in[11];
  const float* k_is   = (const float*)d_in[12];
  const float* wv     = (const float*)d_in[13];
  const float* wv_s   = (const float*)d_in[14];
  const float* v_is   = (const float*)d_in[15];
  const float* wkvx   = (const float*)d_in[16];
  const float* qln_w  = (const float*)d_in[17];
  const float* qln_b  = (const float*)d_in[18];
  const float* kln_w  = (const float*)d_in[19];
  const float* kln_b  = (const float*)d_in[20];
  const float* qxln_w = (const float*)d_in[21];
  const float* qxln_b = (const float*)d_in[22];
  const float* kxln_w = (const float*)d_in[23];
  const float* kxln_b = (const float*)d_in[24];
  const float* wproj  = (const float*)d_in[25];
  const float* p_ws   = (const float*)d_in[26];
  const float* p_is   = (const float*)d_in[27];
  const float* smooth = (const float*)d_in[28];

  char* ws = (char*)d_ws;
  size_t off = 0;
  auto alloc = [&](size_t bytes) {
    char* p = ws + off;
    off += (bytes + 255) & ~(size_t)255;
    return p;
  };
  uint8_t*  Aq    = (uint8_t*)alloc((size_t)4096 * 2048);
  uint8_t*  Wcat  = (uint8_t*)alloc((size_t)6144 * 2048);
  uint8_t*  Wpb   = (uint8_t*)alloc((size_t)2048 * 4096);
  uint16_t* Wkvxh = (uint16_t*)alloc((size_t)2048 * 2048 * 2);
  uint16_t* Wkvxl = (uint16_t*)alloc((size_t)2048 * 2048 * 2);
  uint16_t* condh = (uint16_t*)alloc((size_t)1024 * 2048 * 2);
  uint16_t* condl = (uint16_t*)alloc((size_t)1024 * 2048 * 2);
  uint16_t* Qh    = (uint16_t*)alloc((size_t)4096 * 16 * 128 * 2);
  uint16_t* Qxh   = (uint16_t*)alloc((size_t)4096 * 16 * 128 * 2);
  uint16_t* Kf    = (uint16_t*)alloc((size_t)4096 * 8 * 128 * 2);
  uint16_t* Vtf   = (uint16_t*)alloc((size_t)4096 * 8 * 128 * 2);
  uint16_t* Kxf   = (uint16_t*)alloc((size_t)1024 * 8 * 128 * 2);
  uint16_t* Vxtf  = (uint16_t*)alloc((size_t)1024 * 8 * 128 * 2);
  uint8_t*  catq  = (uint8_t*)alloc((size_t)4096 * 4096);
  float* scales   = (float*)alloc(256);
  if (ws_size < off) return;

  k_prep<<<2048, 256, 0, stream>>>(wq, wqx, wk, wv, wkvx, wproj, cond,
      q_is, wq_s, qx_is, wqx_s, k_is, wk_s, v_is, wv_s, p_is, p_ws,
      Wcat, Wpb, Wkvxh, Wkvxl, condh, condl, scales);

  k_ln_quant<<<4096, 256, 0, stream>>>(hidden, ln_w, ln_b, q_is, Aq);

  k_gemm8<0><<<dim3(48, 32), 256, 0, stream>>>(Aq, Wcat,
      4096, 6144, 2048, scales, qln_w, qln_b, kln_w, kln_b, qxln_w, qxln_b,
      Qh, Qxh, Kf, Vtf, nullptr);

  k_kvx<<<dim3(16, 16), 256, 0, stream>>>(condh, condl, Wkvxh, Wkvxl,
      kxln_w, kxln_b, Kxf, Vxtf);

  k_attn<<<dim3(16, 16, 4), 512, 0, stream>>>(Qh, Qxh, Kf, Vtf, Kxf, Vxtf,
      smooth, catq);

  k_gemm8<2><<<dim3(16, 32), 256, 0, stream>>>(catq, Wpb,
      4096, 2048, 4096, scales, nullptr, nullptr, nullptr, nullptr, nullptr, nullptr,
      nullptr, nullptr, nullptr, nullptr,
      (float*)d_out);
}